// Round 2
// baseline (608.142 us; speedup 1.0000x reference)
//
#include <hip/hip_runtime.h>

// Problem constants (match setup_inputs)
#define NN 50000      // nodes
#define NE 800000     // edges
#define DIN 256       // 192 + 64
#define DOUT 256

typedef __attribute__((ext_vector_type(8))) short bf16x8;          // 8 bf16 = 4 VGPRs
typedef __attribute__((ext_vector_type(4))) float f32x4;           // MFMA acc
typedef __attribute__((ext_vector_type(8))) unsigned short u16x8;  // 8 bf16 store

__device__ __forceinline__ unsigned short f2bf(float x) {
    unsigned int u = __builtin_bit_cast(unsigned int, x);
    u += 0x7fffu + ((u >> 16) & 1u);        // round-to-nearest-even
    return (unsigned short)(u >> 16);
}
__device__ __forceinline__ float bf2f(unsigned short b) {
    return __builtin_bit_cast(float, ((unsigned int)b) << 16);
}

// ---------------------------------------------------------------------------
// ws layout (new path, ~151.3 MB):
//   h_bf     [NN*256]  bf16  (25.6 MB)
//   wt_bf    [256*256] bf16
//   featn_bf [NN*192]  bf16  (19.2 MB; feat * odeg_inv, pre-rounded)
//   row_off  [NN+2]    int
//   odeg_inv [NN]      float
//   cursor   [NN]      int
//   bsum     [256]     int
//   perm     [NE]      int   (src id, CSR order)    } first 2*NN ints alias
//   eperm    [NE*64]   bf16  (edge feats, CSR order)} in_cnt/out_cnt early
// Fallback path (ws < need): perm2 [NE] int2 replaces perm+eperm (~55 MB).
// ---------------------------------------------------------------------------

__global__ __launch_bounds__(256) void zero_meta(int* __restrict__ p, int n) {
    int i = blockIdx.x * 256 + threadIdx.x;
    if (i < n) p[i] = 0;
}

__global__ __launch_bounds__(256) void count_kernel(const int* __restrict__ src,
                                                    const int* __restrict__ dst,
                                                    int* __restrict__ in_cnt,
                                                    int* __restrict__ out_cnt) {
    int e = blockIdx.x * 256 + threadIdx.x;
    if (e < NE) {
        atomicAdd(in_cnt + dst[e], 1);
        atomicAdd(out_cnt + src[e], 1);
    }
}

__global__ __launch_bounds__(256) void scan1(const int* __restrict__ cnt,
                                             int* __restrict__ row_off,
                                             int* __restrict__ bsum) {
    __shared__ int tmp[256];
    int tid = threadIdx.x;
    int i = blockIdx.x * 256 + tid;
    int v = (i < NN) ? cnt[i] : 0;
    tmp[tid] = v;
    __syncthreads();
#pragma unroll
    for (int off = 1; off < 256; off <<= 1) {
        int t = (tid >= off) ? tmp[tid - off] : 0;
        __syncthreads();
        if (tid >= off) tmp[tid] += t;
        __syncthreads();
    }
    if (i < NN) row_off[i] = tmp[tid] - v;   // exclusive
    if (tid == 255) bsum[blockIdx.x] = tmp[255];
}

__global__ __launch_bounds__(256) void scan2(int* __restrict__ bsum, int nb) {
    __shared__ int tmp[256];
    int tid = threadIdx.x;
    int v = (tid < nb) ? bsum[tid] : 0;
    tmp[tid] = v;
    __syncthreads();
#pragma unroll
    for (int off = 1; off < 256; off <<= 1) {
        int t = (tid >= off) ? tmp[tid - off] : 0;
        __syncthreads();
        if (tid >= off) tmp[tid] += t;
        __syncthreads();
    }
    if (tid < nb) bsum[tid] = tmp[tid] - v;  // exclusive
}

// Finish row_off scan; seed cursor; fold in odeg_inv (out_cnt still live here).
__global__ __launch_bounds__(256) void scan3(int* __restrict__ row_off,
                                             int* __restrict__ cursor,
                                             float* __restrict__ odeg_inv,
                                             const int* __restrict__ out_cnt,
                                             const int* __restrict__ bsum) {
    int i = blockIdx.x * 256 + threadIdx.x;
    if (i < NN) {
        int v = row_off[i] + bsum[i >> 8];
        row_off[i] = v;
        cursor[i] = v;
        odeg_inv[i] = rsqrtf((float)max(out_cnt[i], 1));
    }
    if (i == NN) row_off[NN] = NE;
}

// W[k][n] fp32 -> wt[n][k] bf16
__global__ __launch_bounds__(256) void wconv(const float* __restrict__ W,
                                             unsigned short* __restrict__ wt) {
    int n = blockIdx.x, k = threadIdx.x;
    wt[n * 256 + k] = f2bf(W[k * 256 + n]);
}

// featn_bf[n][k] = bf16(feat[n][k] * odeg_inv[n]).
__global__ __launch_bounds__(256) void featconv(const float* __restrict__ feat,
                                                const float* __restrict__ odeg_inv,
                                                unsigned short* __restrict__ featn) {
    int node = blockIdx.x * 4 + (threadIdx.x >> 6);
    int lane = threadIdx.x & 63;
    if (node >= NN || lane >= 48) return;
    float s = odeg_inv[node];
    float4 v = *(const float4*)(feat + (size_t)node * 192 + lane * 4);
    ushort4 o;
    o.x = f2bf(v.x * s); o.y = f2bf(v.y * s);
    o.z = f2bf(v.z * s); o.w = f2bf(v.w * s);
    *(ushort4*)(featn + (size_t)node * 192 + lane * 4) = o;
}

// NEW: CSR fill + edge-feature permute+bf16-convert.
// perm[pos] = src[e];  eperm[pos*64 .. +64] = bf16(edge_feat[e][0..64]).
// Sequential 256B read per thread, scattered aligned 128B write (full lines).
__global__ __launch_bounds__(256) void fill_kernel(const int* __restrict__ src,
                                                   const int* __restrict__ dst,
                                                   int* __restrict__ cursor,
                                                   int* __restrict__ perm,
                                                   unsigned short* __restrict__ eperm,
                                                   const float* __restrict__ edge_feat) {
    int e = blockIdx.x * 256 + threadIdx.x;
    if (e >= NE) return;
    int pos = atomicAdd(cursor + dst[e], 1);
    perm[pos] = src[e];
    const float* ef = edge_feat + (size_t)e * 64;
    unsigned short* op = eperm + (size_t)pos * 64;
#pragma unroll
    for (int k = 0; k < 8; ++k) {
        float4 a = *(const float4*)(ef + k * 8);
        float4 b = *(const float4*)(ef + k * 8 + 4);
        u16x8 o;
        o[0] = f2bf(a.x); o[1] = f2bf(a.y); o[2] = f2bf(a.z); o[3] = f2bf(a.w);
        o[4] = f2bf(b.x); o[5] = f2bf(b.y); o[6] = f2bf(b.z); o[7] = f2bf(b.w);
        *(u16x8*)(op + k * 8) = o;
    }
}

// NEW aggregate: one wave per dst node.
// Lanes 0-47: feat part, bf16 gathers (8 B/lane) from featn (L3-resident).
// Lanes 48-63: edge part, SEQUENTIAL bf16 reads from eperm (CSR-ordered).
__global__ __launch_bounds__(256) void aggregate_kernel(const unsigned short* __restrict__ featn,
                                                        const unsigned short* __restrict__ eperm,
                                                        const int* __restrict__ row_off,
                                                        const int* __restrict__ perm,
                                                        unsigned short* __restrict__ h_bf) {
    int node = blockIdx.x * 4 + (threadIdx.x >> 6);
    int lane = threadIdx.x & 63;
    if (node >= NN) return;
    int start = row_off[node];
    int end   = row_off[node + 1];

    float4 acc = make_float4(0.f, 0.f, 0.f, 0.f);

    if (lane < 48) {
        const unsigned short* fb = featn + lane * 4;
        for (int i = start; i < end; i += 8) {
            int s[8];
#pragma unroll
            for (int j = 0; j < 8; ++j) s[j] = perm[min(i + j, end - 1)];
            ushort4 u[8];
#pragma unroll
            for (int j = 0; j < 8; ++j)
                u[j] = *(const ushort4*)(fb + (size_t)s[j] * 192);
#pragma unroll
            for (int j = 0; j < 8; ++j) {
                float w = (i + j < end) ? 1.f : 0.f;
                acc.x = fmaf(bf2f(u[j].x), w, acc.x);
                acc.y = fmaf(bf2f(u[j].y), w, acc.y);
                acc.z = fmaf(bf2f(u[j].z), w, acc.z);
                acc.w = fmaf(bf2f(u[j].w), w, acc.w);
            }
        }
    } else {
        const unsigned short* eb = eperm + (lane - 48) * 4;
        for (int i = start; i < end; i += 8) {
            ushort4 u[8];
#pragma unroll
            for (int j = 0; j < 8; ++j)
                u[j] = *(const ushort4*)(eb + (size_t)min(i + j, end - 1) * 64);
#pragma unroll
            for (int j = 0; j < 8; ++j) {
                float w = (i + j < end) ? 1.f : 0.f;
                acc.x = fmaf(bf2f(u[j].x), w, acc.x);
                acc.y = fmaf(bf2f(u[j].y), w, acc.y);
                acc.z = fmaf(bf2f(u[j].z), w, acc.z);
                acc.w = fmaf(bf2f(u[j].w), w, acc.w);
            }
        }
    }

    ushort4 o;
    o.x = f2bf(acc.x); o.y = f2bf(acc.y);
    o.z = f2bf(acc.z); o.w = f2bf(acc.w);
    *(ushort4*)(h_bf + (size_t)node * 256 + lane * 4) = o;
}

// -------- fallback path (ws too small): round-1 verified kernels -----------
__global__ __launch_bounds__(256) void fill_fb(const int* __restrict__ src,
                                               const int* __restrict__ dst,
                                               int* __restrict__ cursor,
                                               int2* __restrict__ perm2) {
    int e = blockIdx.x * 256 + threadIdx.x;
    if (e < NE) {
        int d = dst[e];
        int pos = atomicAdd(cursor + d, 1);
        perm2[pos] = make_int2(e, src[e]);
    }
}

__global__ __launch_bounds__(256) void aggregate_fb(const unsigned short* __restrict__ featn,
                                                    const float* __restrict__ edge_feat,
                                                    const int* __restrict__ row_off,
                                                    const int2* __restrict__ perm2,
                                                    unsigned short* __restrict__ h_bf) {
    int node = blockIdx.x * 4 + (threadIdx.x >> 6);
    int lane = threadIdx.x & 63;
    if (node >= NN) return;
    int start = row_off[node];
    int end   = row_off[node + 1];

    float4 acc = make_float4(0.f, 0.f, 0.f, 0.f);

    if (lane < 48) {
        const unsigned short* fb = featn + lane * 4;
        for (int i = start; i < end; i += 8) {
            int2 p[8];
#pragma unroll
            for (int j = 0; j < 8; ++j) p[j] = perm2[min(i + j, end - 1)];
            ushort4 u[8];
#pragma unroll
            for (int j = 0; j < 8; ++j)
                u[j] = *(const ushort4*)(fb + (size_t)p[j].y * 192);
#pragma unroll
            for (int j = 0; j < 8; ++j) {
                float w = (i + j < end) ? 1.f : 0.f;
                acc.x = fmaf(bf2f(u[j].x), w, acc.x);
                acc.y = fmaf(bf2f(u[j].y), w, acc.y);
                acc.z = fmaf(bf2f(u[j].z), w, acc.z);
                acc.w = fmaf(bf2f(u[j].w), w, acc.w);
            }
        }
    } else {
        const float* eb = edge_feat + (lane - 48) * 4;
        for (int i = start; i < end; i += 8) {
            int2 p[8];
#pragma unroll
            for (int j = 0; j < 8; ++j) p[j] = perm2[min(i + j, end - 1)];
            float4 v[8];
#pragma unroll
            for (int j = 0; j < 8; ++j)
                v[j] = *(const float4*)(eb + (size_t)p[j].x * 64);
#pragma unroll
            for (int j = 0; j < 8; ++j) {
                float w = (i + j < end) ? 1.f : 0.f;
                acc.x = fmaf(v[j].x, w, acc.x);
                acc.y = fmaf(v[j].y, w, acc.y);
                acc.z = fmaf(v[j].z, w, acc.z);
                acc.w = fmaf(v[j].w, w, acc.w);
            }
        }
    }

    ushort4 o;
    o.x = f2bf(acc.x); o.y = f2bf(acc.y);
    o.z = f2bf(acc.z); o.w = f2bf(acc.w);
    *(ushort4*)(h_bf + (size_t)node * 256 + lane * 4) = o;
}

// MFMA GEMM: out = (h_bf @ W) * rsqrt(max(in_deg,1))[:,None] + bias
// Block = 16 rows x 256 cols; 4 waves side-by-side on cols (64 each).
// C/D: row = (lane>>4)*4 + reg, col = lane&15   [guide §3, m89-verified]
__global__ __launch_bounds__(256) void gemm_mfma(const unsigned short* __restrict__ h_bf,
                                                 const unsigned short* __restrict__ wt_bf,
                                                 const float* __restrict__ bias,
                                                 const int* __restrict__ row_off,
                                                 float* __restrict__ out) {
    int wave = threadIdx.x >> 6;
    int lane = threadIdx.x & 63;
    int m16  = lane & 15;
    int quad = lane >> 4;
    int rbase = blockIdx.x * 16;
    int cbase = wave * 64;

    const unsigned short* arow = h_bf + (size_t)(rbase + m16) * 256 + quad * 8;
    const unsigned short* b0p = wt_bf + (size_t)(cbase +  0 + m16) * 256 + quad * 8;
    const unsigned short* b1p = wt_bf + (size_t)(cbase + 16 + m16) * 256 + quad * 8;
    const unsigned short* b2p = wt_bf + (size_t)(cbase + 32 + m16) * 256 + quad * 8;
    const unsigned short* b3p = wt_bf + (size_t)(cbase + 48 + m16) * 256 + quad * 8;

    f32x4 acc0 = {0.f, 0.f, 0.f, 0.f};
    f32x4 acc1 = {0.f, 0.f, 0.f, 0.f};
    f32x4 acc2 = {0.f, 0.f, 0.f, 0.f};
    f32x4 acc3 = {0.f, 0.f, 0.f, 0.f};

#pragma unroll
    for (int k0 = 0; k0 < 256; k0 += 32) {
        bf16x8 a  = *(const bf16x8*)(arow + k0);
        bf16x8 b0 = *(const bf16x8*)(b0p + k0);
        bf16x8 b1 = *(const bf16x8*)(b1p + k0);
        bf16x8 b2 = *(const bf16x8*)(b2p + k0);
        bf16x8 b3 = *(const bf16x8*)(b3p + k0);
        acc0 = __builtin_amdgcn_mfma_f32_16x16x32_bf16(a, b0, acc0, 0, 0, 0);
        acc1 = __builtin_amdgcn_mfma_f32_16x16x32_bf16(a, b1, acc1, 0, 0, 0);
        acc2 = __builtin_amdgcn_mfma_f32_16x16x32_bf16(a, b2, acc2, 0, 0, 0);
        acc3 = __builtin_amdgcn_mfma_f32_16x16x32_bf16(a, b3, acc3, 0, 0, 0);
    }

    // in-degree scales for this lane's 4 output rows
    int grow0 = rbase + quad * 4;
    float s[4];
    int ro_prev = row_off[grow0];
#pragma unroll
    for (int r = 0; r < 4; ++r) {
        int nx = row_off[grow0 + r + 1];
        s[r] = rsqrtf((float)max(nx - ro_prev, 1));
        ro_prev = nx;
    }

    float bv0 = bias[cbase +  0 + m16];
    float bv1 = bias[cbase + 16 + m16];
    float bv2 = bias[cbase + 32 + m16];
    float bv3 = bias[cbase + 48 + m16];

#pragma unroll
    for (int r = 0; r < 4; ++r) {
        size_t rowoff = (size_t)(grow0 + r) * DOUT;
        out[rowoff + cbase +  0 + m16] = acc0[r] * s[r] + bv0;
        out[rowoff + cbase + 16 + m16] = acc1[r] * s[r] + bv1;
        out[rowoff + cbase + 32 + m16] = acc2[r] * s[r] + bv2;
        out[rowoff + cbase + 48 + m16] = acc3[r] * s[r] + bv3;
    }
}

extern "C" void kernel_launch(void* const* d_in, const int* in_sizes, int n_in,
                              void* d_out, int out_size, void* d_ws, size_t ws_size,
                              hipStream_t stream) {
    const float* feat      = (const float*)d_in[0];
    const float* edge_feat = (const float*)d_in[1];
    const int*   src       = (const int*)d_in[2];
    const int*   dst       = (const int*)d_in[3];
    const float* W         = (const float*)d_in[4];
    const float* bias      = (const float*)d_in[5];
    float* out = (float*)d_out;

    unsigned short* h_bf    = (unsigned short*)d_ws;                 // NN*256 bf16
    unsigned short* wt_bf   = h_bf + (size_t)NN * DIN;               // 256*256 bf16
    unsigned short* featn   = wt_bf + 256 * 256;                     // NN*192 bf16
    int*   row_off  = (int*)(featn + (size_t)NN * 192);              // NN+2
    float* odeg_inv = (float*)(row_off + NN + 2);                    // NN
    int*   cursor   = (int*)(odeg_inv + NN);                         // NN
    int*   bsum     = cursor + NN;                                   // 256
    int*   perm     = bsum + 256;                                    // NE int
    unsigned short* eperm = (unsigned short*)(perm + NE);            // NE*64 bf16
    int2*  perm2    = (int2*)perm;                                   // fallback alias
    int*   in_cnt   = perm;                                          // alias (early)
    int*   out_cnt  = in_cnt + NN;                                   // alias (early)

    // ws requirement of the new path
    size_t need = (size_t)((char*)(eperm + (size_t)NE * 64) - (char*)d_ws);
    bool big_ws = (ws_size >= need);

    const int SCAN_BLOCKS = (NN + 255) / 256;   // 196

    zero_meta<<<(2 * NN + 255) / 256, 256, 0, stream>>>(in_cnt, 2 * NN);
    count_kernel<<<(NE + 255) / 256, 256, 0, stream>>>(src, dst, in_cnt, out_cnt);
    scan1<<<SCAN_BLOCKS, 256, 0, stream>>>(in_cnt, row_off, bsum);
    scan2<<<1, 256, 0, stream>>>(bsum, SCAN_BLOCKS);
    scan3<<<(NN + 256) / 256, 256, 0, stream>>>(row_off, cursor, odeg_inv, out_cnt, bsum);
    wconv<<<256, 256, 0, stream>>>(W, wt_bf);
    featconv<<<(NN + 3) / 4, 256, 0, stream>>>(feat, odeg_inv, featn);
    if (big_ws) {
        fill_kernel<<<(NE + 255) / 256, 256, 0, stream>>>(src, dst, cursor, perm,
                                                          eperm, edge_feat);
        aggregate_kernel<<<(NN + 3) / 4, 256, 0, stream>>>(featn, eperm, row_off,
                                                           perm, h_bf);
    } else {
        fill_fb<<<(NE + 255) / 256, 256, 0, stream>>>(src, dst, cursor, perm2);
        aggregate_fb<<<(NN + 3) / 4, 256, 0, stream>>>(featn, edge_feat, row_off,
                                                       perm2, h_bf);
    }
    gemm_mfma<<<NN / 16, 256, 0, stream>>>(h_bf, wt_bf, bias, row_off, out);
}

// Round 3
// 579.000 us; speedup vs baseline: 1.0503x; 1.0503x over previous
//
#include <hip/hip_runtime.h>

// Problem constants (match setup_inputs)
#define NN 50000      // nodes
#define NE 800000     // edges
#define DIN 256       // 192 + 64
#define DOUT 256

typedef __attribute__((ext_vector_type(8))) short bf16x8;          // 8 bf16 = 4 VGPRs
typedef __attribute__((ext_vector_type(4))) float f32x4;           // MFMA acc

__device__ __forceinline__ unsigned short f2bf(float x) {
    unsigned int u = __builtin_bit_cast(unsigned int, x);
    u += 0x7fffu + ((u >> 16) & 1u);        // round-to-nearest-even
    return (unsigned short)(u >> 16);
}
__device__ __forceinline__ float bf2f(unsigned short b) {
    return __builtin_bit_cast(float, ((unsigned int)b) << 16);
}

// ---------------------------------------------------------------------------
// ws layout, big path (~151.3 MB), ALL big arrays 256B-aligned:
//   h_bf     [NN*256]  bf16   off 0
//   wt_bf    [256*256] bf16   off 25,600,000
//   featn_bf [NN*192]  bf16   off 25,731,072
//   eperm    [NE*64]   bf16   off 44,931,072  (256B-aligned: pos*128 = full line)
//   perm     [NE]      int    (src id, CSR order; first 2*NN alias in/out_cnt)
//   row_off  [NN+2]    int
//   odeg_inv [NN]      float
//   cursor   [NN]      int
//   bsum     [256]     int
// Fallback path (small ws): round-1 layout, perm2[NE] int2 after bsum.
// ---------------------------------------------------------------------------

__global__ __launch_bounds__(256) void zero_meta(int* __restrict__ p, int n) {
    int i = blockIdx.x * 256 + threadIdx.x;
    if (i < n) p[i] = 0;
}

__global__ __launch_bounds__(256) void count_kernel(const int* __restrict__ src,
                                                    const int* __restrict__ dst,
                                                    int* __restrict__ in_cnt,
                                                    int* __restrict__ out_cnt) {
    int e = blockIdx.x * 256 + threadIdx.x;
    if (e < NE) {
        atomicAdd(in_cnt + dst[e], 1);
        atomicAdd(out_cnt + src[e], 1);
    }
}

__global__ __launch_bounds__(256) void scan1(const int* __restrict__ cnt,
                                             int* __restrict__ row_off,
                                             int* __restrict__ bsum) {
    __shared__ int tmp[256];
    int tid = threadIdx.x;
    int i = blockIdx.x * 256 + tid;
    int v = (i < NN) ? cnt[i] : 0;
    tmp[tid] = v;
    __syncthreads();
#pragma unroll
    for (int off = 1; off < 256; off <<= 1) {
        int t = (tid >= off) ? tmp[tid - off] : 0;
        __syncthreads();
        if (tid >= off) tmp[tid] += t;
        __syncthreads();
    }
    if (i < NN) row_off[i] = tmp[tid] - v;   // exclusive
    if (tid == 255) bsum[blockIdx.x] = tmp[255];
}

__global__ __launch_bounds__(256) void scan2(int* __restrict__ bsum, int nb) {
    __shared__ int tmp[256];
    int tid = threadIdx.x;
    int v = (tid < nb) ? bsum[tid] : 0;
    tmp[tid] = v;
    __syncthreads();
#pragma unroll
    for (int off = 1; off < 256; off <<= 1) {
        int t = (tid >= off) ? tmp[tid - off] : 0;
        __syncthreads();
        if (tid >= off) tmp[tid] += t;
        __syncthreads();
    }
    if (tid < nb) bsum[tid] = tmp[tid] - v;  // exclusive
}

// Finish row_off scan; seed cursor; fold in odeg_inv (out_cnt still live here).
__global__ __launch_bounds__(256) void scan3(int* __restrict__ row_off,
                                             int* __restrict__ cursor,
                                             float* __restrict__ odeg_inv,
                                             const int* __restrict__ out_cnt,
                                             const int* __restrict__ bsum) {
    int i = blockIdx.x * 256 + threadIdx.x;
    if (i < NN) {
        int v = row_off[i] + bsum[i >> 8];
        row_off[i] = v;
        cursor[i] = v;
        odeg_inv[i] = rsqrtf((float)max(out_cnt[i], 1));
    }
    if (i == NN) row_off[NN] = NE;
}

// W[k][n] fp32 -> wt[n][k] bf16
__global__ __launch_bounds__(256) void wconv(const float* __restrict__ W,
                                             unsigned short* __restrict__ wt) {
    int n = blockIdx.x, k = threadIdx.x;
    wt[n * 256 + k] = f2bf(W[k * 256 + n]);
}

// featn_bf[n][k] = bf16(feat[n][k] * odeg_inv[n]).
__global__ __launch_bounds__(256) void featconv(const float* __restrict__ feat,
                                                const float* __restrict__ odeg_inv,
                                                unsigned short* __restrict__ featn) {
    int node = blockIdx.x * 4 + (threadIdx.x >> 6);
    int lane = threadIdx.x & 63;
    if (node >= NN || lane >= 48) return;
    float s = odeg_inv[node];
    float4 v = *(const float4*)(feat + (size_t)node * 192 + lane * 4);
    ushort4 o;
    o.x = f2bf(v.x * s); o.y = f2bf(v.y * s);
    o.z = f2bf(v.z * s); o.w = f2bf(v.w * s);
    *(ushort4*)(featn + (size_t)node * 192 + lane * 4) = o;
}

// Wave-cooperative CSR fill: 16 lanes per edge.
// Lane sub reads float4 (16B) of edge_feat; writes ushort4 (8B) of eperm.
// Per edge: read = 256B contiguous burst, write = ONE full 128B line
// (eperm 256B-aligned, record = pos*128). Leader lane does the atomic,
// position broadcast via shfl. Fixes round-2's 1.7x write amplification.
__global__ __launch_bounds__(256) void fill_kernel(const int* __restrict__ src,
                                                   const int* __restrict__ dst,
                                                   int* __restrict__ cursor,
                                                   int* __restrict__ perm,
                                                   unsigned short* __restrict__ eperm,
                                                   const float* __restrict__ edge_feat) {
    int tid = threadIdx.x;
    int e   = blockIdx.x * 16 + (tid >> 4);   // 16 edges per block
    int sub = tid & 15;
    if (e >= NE) return;
    int pos = 0;
    if (sub == 0) {
        pos = atomicAdd(cursor + dst[e], 1);
        perm[pos] = src[e];
    }
    pos = __shfl(pos, 0, 16);                 // broadcast within 16-lane group
    float4 v = *(const float4*)(edge_feat + (size_t)e * 64 + sub * 4);
    ushort4 o;
    o.x = f2bf(v.x); o.y = f2bf(v.y); o.z = f2bf(v.z); o.w = f2bf(v.w);
    *(ushort4*)(eperm + (size_t)pos * 64 + sub * 4) = o;
}

// Aggregate: one wave per dst node.
// Lanes 0-47: feat part, bf16 gathers (8 B/lane) from featn (L3-fresh).
// Lanes 48-63: edge part, SEQUENTIAL bf16 reads from eperm (CSR-ordered).
__global__ __launch_bounds__(256) void aggregate_kernel(const unsigned short* __restrict__ featn,
                                                        const unsigned short* __restrict__ eperm,
                                                        const int* __restrict__ row_off,
                                                        const int* __restrict__ perm,
                                                        unsigned short* __restrict__ h_bf) {
    int node = blockIdx.x * 4 + (threadIdx.x >> 6);
    int lane = threadIdx.x & 63;
    if (node >= NN) return;
    int start = row_off[node];
    int end   = row_off[node + 1];

    float4 acc = make_float4(0.f, 0.f, 0.f, 0.f);

    if (lane < 48) {
        const unsigned short* fb = featn + lane * 4;
        for (int i = start; i < end; i += 8) {
            int s[8];
#pragma unroll
            for (int j = 0; j < 8; ++j) s[j] = perm[min(i + j, end - 1)];
            ushort4 u[8];
#pragma unroll
            for (int j = 0; j < 8; ++j)
                u[j] = *(const ushort4*)(fb + (size_t)s[j] * 192);
#pragma unroll
            for (int j = 0; j < 8; ++j) {
                float w = (i + j < end) ? 1.f : 0.f;
                acc.x = fmaf(bf2f(u[j].x), w, acc.x);
                acc.y = fmaf(bf2f(u[j].y), w, acc.y);
                acc.z = fmaf(bf2f(u[j].z), w, acc.z);
                acc.w = fmaf(bf2f(u[j].w), w, acc.w);
            }
        }
    } else {
        const unsigned short* eb = eperm + (lane - 48) * 4;
        for (int i = start; i < end; i += 8) {
            ushort4 u[8];
#pragma unroll
            for (int j = 0; j < 8; ++j)
                u[j] = *(const ushort4*)(eb + (size_t)min(i + j, end - 1) * 64);
#pragma unroll
            for (int j = 0; j < 8; ++j) {
                float w = (i + j < end) ? 1.f : 0.f;
                acc.x = fmaf(bf2f(u[j].x), w, acc.x);
                acc.y = fmaf(bf2f(u[j].y), w, acc.y);
                acc.z = fmaf(bf2f(u[j].z), w, acc.z);
                acc.w = fmaf(bf2f(u[j].w), w, acc.w);
            }
        }
    }

    ushort4 o;
    o.x = f2bf(acc.x); o.y = f2bf(acc.y);
    o.z = f2bf(acc.z); o.w = f2bf(acc.w);
    *(ushort4*)(h_bf + (size_t)node * 256 + lane * 4) = o;
}

// -------- fallback path (ws too small): round-1 verified kernels -----------
__global__ __launch_bounds__(256) void fill_fb(const int* __restrict__ src,
                                               const int* __restrict__ dst,
                                               int* __restrict__ cursor,
                                               int2* __restrict__ perm2) {
    int e = blockIdx.x * 256 + threadIdx.x;
    if (e < NE) {
        int d = dst[e];
        int pos = atomicAdd(cursor + d, 1);
        perm2[pos] = make_int2(e, src[e]);
    }
}

__global__ __launch_bounds__(256) void aggregate_fb(const unsigned short* __restrict__ featn,
                                                    const float* __restrict__ edge_feat,
                                                    const int* __restrict__ row_off,
                                                    const int2* __restrict__ perm2,
                                                    unsigned short* __restrict__ h_bf) {
    int node = blockIdx.x * 4 + (threadIdx.x >> 6);
    int lane = threadIdx.x & 63;
    if (node >= NN) return;
    int start = row_off[node];
    int end   = row_off[node + 1];

    float4 acc = make_float4(0.f, 0.f, 0.f, 0.f);

    if (lane < 48) {
        const unsigned short* fb = featn + lane * 4;
        for (int i = start; i < end; i += 8) {
            int2 p[8];
#pragma unroll
            for (int j = 0; j < 8; ++j) p[j] = perm2[min(i + j, end - 1)];
            ushort4 u[8];
#pragma unroll
            for (int j = 0; j < 8; ++j)
                u[j] = *(const ushort4*)(fb + (size_t)p[j].y * 192);
#pragma unroll
            for (int j = 0; j < 8; ++j) {
                float w = (i + j < end) ? 1.f : 0.f;
                acc.x = fmaf(bf2f(u[j].x), w, acc.x);
                acc.y = fmaf(bf2f(u[j].y), w, acc.y);
                acc.z = fmaf(bf2f(u[j].z), w, acc.z);
                acc.w = fmaf(bf2f(u[j].w), w, acc.w);
            }
        }
    } else {
        const float* eb = edge_feat + (lane - 48) * 4;
        for (int i = start; i < end; i += 8) {
            int2 p[8];
#pragma unroll
            for (int j = 0; j < 8; ++j) p[j] = perm2[min(i + j, end - 1)];
            float4 v[8];
#pragma unroll
            for (int j = 0; j < 8; ++j)
                v[j] = *(const float4*)(eb + (size_t)p[j].x * 64);
#pragma unroll
            for (int j = 0; j < 8; ++j) {
                float w = (i + j < end) ? 1.f : 0.f;
                acc.x = fmaf(v[j].x, w, acc.x);
                acc.y = fmaf(v[j].y, w, acc.y);
                acc.z = fmaf(v[j].z, w, acc.z);
                acc.w = fmaf(v[j].w, w, acc.w);
            }
        }
    }

    ushort4 o;
    o.x = f2bf(acc.x); o.y = f2bf(acc.y);
    o.z = f2bf(acc.z); o.w = f2bf(acc.w);
    *(ushort4*)(h_bf + (size_t)node * 256 + lane * 4) = o;
}

// MFMA GEMM: out = (h_bf @ W) * rsqrt(max(in_deg,1))[:,None] + bias
// Block = 16 rows x 256 cols; 4 waves side-by-side on cols (64 each).
// C/D: row = (lane>>4)*4 + reg, col = lane&15   [guide §3, m89-verified]
__global__ __launch_bounds__(256) void gemm_mfma(const unsigned short* __restrict__ h_bf,
                                                 const unsigned short* __restrict__ wt_bf,
                                                 const float* __restrict__ bias,
                                                 const int* __restrict__ row_off,
                                                 float* __restrict__ out) {
    int wave = threadIdx.x >> 6;
    int lane = threadIdx.x & 63;
    int m16  = lane & 15;
    int quad = lane >> 4;
    int rbase = blockIdx.x * 16;
    int cbase = wave * 64;

    const unsigned short* arow = h_bf + (size_t)(rbase + m16) * 256 + quad * 8;
    const unsigned short* b0p = wt_bf + (size_t)(cbase +  0 + m16) * 256 + quad * 8;
    const unsigned short* b1p = wt_bf + (size_t)(cbase + 16 + m16) * 256 + quad * 8;
    const unsigned short* b2p = wt_bf + (size_t)(cbase + 32 + m16) * 256 + quad * 8;
    const unsigned short* b3p = wt_bf + (size_t)(cbase + 48 + m16) * 256 + quad * 8;

    f32x4 acc0 = {0.f, 0.f, 0.f, 0.f};
    f32x4 acc1 = {0.f, 0.f, 0.f, 0.f};
    f32x4 acc2 = {0.f, 0.f, 0.f, 0.f};
    f32x4 acc3 = {0.f, 0.f, 0.f, 0.f};

#pragma unroll
    for (int k0 = 0; k0 < 256; k0 += 32) {
        bf16x8 a  = *(const bf16x8*)(arow + k0);
        bf16x8 b0 = *(const bf16x8*)(b0p + k0);
        bf16x8 b1 = *(const bf16x8*)(b1p + k0);
        bf16x8 b2 = *(const bf16x8*)(b2p + k0);
        bf16x8 b3 = *(const bf16x8*)(b3p + k0);
        acc0 = __builtin_amdgcn_mfma_f32_16x16x32_bf16(a, b0, acc0, 0, 0, 0);
        acc1 = __builtin_amdgcn_mfma_f32_16x16x32_bf16(a, b1, acc1, 0, 0, 0);
        acc2 = __builtin_amdgcn_mfma_f32_16x16x32_bf16(a, b2, acc2, 0, 0, 0);
        acc3 = __builtin_amdgcn_mfma_f32_16x16x32_bf16(a, b3, acc3, 0, 0, 0);
    }

    // in-degree scales for this lane's 4 output rows
    int grow0 = rbase + quad * 4;
    float s[4];
    int ro_prev = row_off[grow0];
#pragma unroll
    for (int r = 0; r < 4; ++r) {
        int nx = row_off[grow0 + r + 1];
        s[r] = rsqrtf((float)max(nx - ro_prev, 1));
        ro_prev = nx;
    }

    float bv0 = bias[cbase +  0 + m16];
    float bv1 = bias[cbase + 16 + m16];
    float bv2 = bias[cbase + 32 + m16];
    float bv3 = bias[cbase + 48 + m16];

#pragma unroll
    for (int r = 0; r < 4; ++r) {
        size_t rowoff = (size_t)(grow0 + r) * DOUT;
        out[rowoff + cbase +  0 + m16] = acc0[r] * s[r] + bv0;
        out[rowoff + cbase + 16 + m16] = acc1[r] * s[r] + bv1;
        out[rowoff + cbase + 32 + m16] = acc2[r] * s[r] + bv2;
        out[rowoff + cbase + 48 + m16] = acc3[r] * s[r] + bv3;
    }
}

extern "C" void kernel_launch(void* const* d_in, const int* in_sizes, int n_in,
                              void* d_out, int out_size, void* d_ws, size_t ws_size,
                              hipStream_t stream) {
    const float* feat      = (const float*)d_in[0];
    const float* edge_feat = (const float*)d_in[1];
    const int*   src       = (const int*)d_in[2];
    const int*   dst       = (const int*)d_in[3];
    const float* W         = (const float*)d_in[4];
    const float* bias      = (const float*)d_in[5];
    float* out = (float*)d_out;

    // common big arrays (all 256B-aligned by construction)
    unsigned short* h_bf  = (unsigned short*)d_ws;            // NN*256 bf16
    unsigned short* wt_bf = h_bf + (size_t)NN * DIN;          // 256*256 bf16
    unsigned short* featn = wt_bf + 256 * 256;                // NN*192 bf16

    // big path layout: eperm directly after featn (256B-aligned)
    unsigned short* eperm = featn + (size_t)NN * 192;         // NE*64 bf16
    int*   perm_b     = (int*)(eperm + (size_t)NE * 64);      // NE int
    int*   row_off_b  = perm_b + NE;                          // NN+2
    float* odeg_inv_b = (float*)(row_off_b + NN + 2);         // NN
    int*   cursor_b   = (int*)(odeg_inv_b + NN);              // NN
    int*   bsum_b     = cursor_b + NN;                        // 256
    size_t need = (size_t)((char*)(bsum_b + 256) - (char*)d_ws);

    // fallback layout (round-1): meta after featn, perm2 after bsum
    int*   row_off_s  = (int*)(featn + (size_t)NN * 192);
    float* odeg_inv_s = (float*)(row_off_s + NN + 2);
    int*   cursor_s   = (int*)(odeg_inv_s + NN);
    int*   bsum_s     = cursor_s + NN;
    int2*  perm2      = (int2*)(bsum_s + 256);

    bool big_ws = (ws_size >= need);

    int*   row_off  = big_ws ? row_off_b  : row_off_s;
    float* odeg_inv = big_ws ? odeg_inv_b : odeg_inv_s;
    int*   cursor   = big_ws ? cursor_b   : cursor_s;
    int*   bsum     = big_ws ? bsum_b     : bsum_s;
    int*   in_cnt   = big_ws ? perm_b     : (int*)perm2;      // alias (early)
    int*   out_cnt  = in_cnt + NN;                            // alias (early)

    const int SCAN_BLOCKS = (NN + 255) / 256;   // 196

    zero_meta<<<(2 * NN + 255) / 256, 256, 0, stream>>>(in_cnt, 2 * NN);
    count_kernel<<<(NE + 255) / 256, 256, 0, stream>>>(src, dst, in_cnt, out_cnt);
    scan1<<<SCAN_BLOCKS, 256, 0, stream>>>(in_cnt, row_off, bsum);
    scan2<<<1, 256, 0, stream>>>(bsum, SCAN_BLOCKS);
    scan3<<<(NN + 256) / 256, 256, 0, stream>>>(row_off, cursor, odeg_inv, out_cnt, bsum);
    wconv<<<256, 256, 0, stream>>>(W, wt_bf);
    if (big_ws) {
        // fill BEFORE featconv so featn stays L3-resident for aggregate
        fill_kernel<<<NE / 16, 256, 0, stream>>>(src, dst, cursor, perm_b,
                                                 eperm, edge_feat);
        featconv<<<(NN + 3) / 4, 256, 0, stream>>>(feat, odeg_inv, featn);
        aggregate_kernel<<<(NN + 3) / 4, 256, 0, stream>>>(featn, eperm, row_off,
                                                           perm_b, h_bf);
    } else {
        featconv<<<(NN + 3) / 4, 256, 0, stream>>>(feat, odeg_inv, featn);
        fill_fb<<<(NE + 255) / 256, 256, 0, stream>>>(src, dst, cursor, perm2);
        aggregate_fb<<<(NN + 3) / 4, 256, 0, stream>>>(featn, edge_feat, row_off,
                                                       perm2, h_bf);
    }
    gemm_mfma<<<NN / 16, 256, 0, stream>>>(h_bf, wt_bf, bias, row_off, out);
}

// Round 4
// 546.804 us; speedup vs baseline: 1.1122x; 1.0589x over previous
//
#include <hip/hip_runtime.h>

// Problem constants (match setup_inputs)
#define NN 50000      // nodes
#define NE 800000     // edges
#define DIN 256       // 192 + 64
#define DOUT 256

typedef __attribute__((ext_vector_type(8))) short bf16x8;          // 8 bf16 = 4 VGPRs
typedef __attribute__((ext_vector_type(8))) unsigned short u16x8;  // 8 bf16 store
typedef __attribute__((ext_vector_type(4))) float f32x4;           // MFMA acc

__device__ __forceinline__ unsigned short f2bf(float x) {
    unsigned int u = __builtin_bit_cast(unsigned int, x);
    u += 0x7fffu + ((u >> 16) & 1u);        // round-to-nearest-even
    return (unsigned short)(u >> 16);
}
__device__ __forceinline__ float bf2f(unsigned short b) {
    return __builtin_bit_cast(float, ((unsigned int)b) << 16);
}

// ---------------------------------------------------------------------------
// ws layout, big path (~151.3 MB), ALL big arrays 256B-aligned:
//   h_bf     [NN*256]  bf16   off 0
//   wt_bf    [256*256] bf16   off 25,600,000
//   featn_bf [NN*192]  bf16   off 25,731,072
//   eperm    [NE*64]   bf16   off 44,931,072  (256B-aligned: pos*128 = full line)
//   perm     [NE]      int    (src id, CSR order; first 2*NN alias in/out_cnt)
//   row_off  [NN+2]    int
//   odeg_inv [NN]      float
//   cursor   [NN]      int
//   bsum     [256]     int
// Fallback path (small ws): round-1 layout, perm2[NE] int2 after bsum.
// ---------------------------------------------------------------------------

__global__ __launch_bounds__(256) void zero_meta(int* __restrict__ p, int n) {
    int i = blockIdx.x * 256 + threadIdx.x;
    if (i < n) p[i] = 0;
}

__global__ __launch_bounds__(256) void count_kernel(const int* __restrict__ src,
                                                    const int* __restrict__ dst,
                                                    int* __restrict__ in_cnt,
                                                    int* __restrict__ out_cnt) {
    int e = blockIdx.x * 256 + threadIdx.x;
    if (e < NE) {
        atomicAdd(in_cnt + dst[e], 1);
        atomicAdd(out_cnt + src[e], 1);
    }
}

__global__ __launch_bounds__(256) void scan1(const int* __restrict__ cnt,
                                             int* __restrict__ row_off,
                                             int* __restrict__ bsum) {
    __shared__ int tmp[256];
    int tid = threadIdx.x;
    int i = blockIdx.x * 256 + tid;
    int v = (i < NN) ? cnt[i] : 0;
    tmp[tid] = v;
    __syncthreads();
#pragma unroll
    for (int off = 1; off < 256; off <<= 1) {
        int t = (tid >= off) ? tmp[tid - off] : 0;
        __syncthreads();
        if (tid >= off) tmp[tid] += t;
        __syncthreads();
    }
    if (i < NN) row_off[i] = tmp[tid] - v;   // exclusive
    if (tid == 255) bsum[blockIdx.x] = tmp[255];
}

__global__ __launch_bounds__(256) void scan2(int* __restrict__ bsum, int nb) {
    __shared__ int tmp[256];
    int tid = threadIdx.x;
    int v = (tid < nb) ? bsum[tid] : 0;
    tmp[tid] = v;
    __syncthreads();
#pragma unroll
    for (int off = 1; off < 256; off <<= 1) {
        int t = (tid >= off) ? tmp[tid - off] : 0;
        __syncthreads();
        if (tid >= off) tmp[tid] += t;
        __syncthreads();
    }
    if (tid < nb) bsum[tid] = tmp[tid] - v;  // exclusive
}

// Finish row_off scan; seed cursor; fold in odeg_inv (out_cnt still live here).
__global__ __launch_bounds__(256) void scan3(int* __restrict__ row_off,
                                             int* __restrict__ cursor,
                                             float* __restrict__ odeg_inv,
                                             const int* __restrict__ out_cnt,
                                             const int* __restrict__ bsum) {
    int i = blockIdx.x * 256 + threadIdx.x;
    if (i < NN) {
        int v = row_off[i] + bsum[i >> 8];
        row_off[i] = v;
        cursor[i] = v;
        odeg_inv[i] = rsqrtf((float)max(out_cnt[i], 1));
    }
    if (i == NN) row_off[NN] = NE;
}

// W[k][n] fp32 -> wt[n][k] bf16
__global__ __launch_bounds__(256) void wconv(const float* __restrict__ W,
                                             unsigned short* __restrict__ wt) {
    int n = blockIdx.x, k = threadIdx.x;
    wt[n * 256 + k] = f2bf(W[k * 256 + n]);
}

// featn_bf[n][k] = bf16(feat[n][k] * odeg_inv[n]).
__global__ __launch_bounds__(256) void featconv(const float* __restrict__ feat,
                                                const float* __restrict__ odeg_inv,
                                                unsigned short* __restrict__ featn) {
    int node = blockIdx.x * 4 + (threadIdx.x >> 6);
    int lane = threadIdx.x & 63;
    if (node >= NN || lane >= 48) return;
    float s = odeg_inv[node];
    float4 v = *(const float4*)(feat + (size_t)node * 192 + lane * 4);
    ushort4 o;
    o.x = f2bf(v.x * s); o.y = f2bf(v.y * s);
    o.z = f2bf(v.z * s); o.w = f2bf(v.w * s);
    *(ushort4*)(featn + (size_t)node * 192 + lane * 4) = o;
}

// Wave-cooperative CSR fill: 16 lanes per edge.
// Per edge: read = 256B contiguous burst, write = ONE full 128B line
// (eperm 256B-aligned, record = pos*128). Leader lane does the atomic,
// position broadcast via shfl.
__global__ __launch_bounds__(256) void fill_kernel(const int* __restrict__ src,
                                                   const int* __restrict__ dst,
                                                   int* __restrict__ cursor,
                                                   int* __restrict__ perm,
                                                   unsigned short* __restrict__ eperm,
                                                   const float* __restrict__ edge_feat) {
    int tid = threadIdx.x;
    int e   = blockIdx.x * 16 + (tid >> 4);   // 16 edges per block
    int sub = tid & 15;
    if (e >= NE) return;
    int pos = 0;
    if (sub == 0) {
        pos = atomicAdd(cursor + dst[e], 1);
        perm[pos] = src[e];
    }
    pos = __shfl(pos, 0, 16);                 // broadcast within 16-lane group
    float4 v = *(const float4*)(edge_feat + (size_t)e * 64 + sub * 4);
    ushort4 o;
    o.x = f2bf(v.x); o.y = f2bf(v.y); o.z = f2bf(v.z); o.w = f2bf(v.w);
    *(ushort4*)(eperm + (size_t)pos * 64 + sub * 4) = o;
}

// Aggregate v2: one wave per dst node, TWO edges in flight per step.
// lane = (half, l): half = lane>>5 processes CSR positions start+half, +2, ...
// l < 24 : cols [l*8, l*8+8) of feat part  -> 16B bf16x8 gather from featn
// l >= 24: cols [l*8, l*8+8) of edge part  -> 16B sequential read from eperm
// (col map collapses to l*8 since 192 + (l-24)*8 == l*8.)
// Unroll 4 -> 8 edges per wave-step. Final __shfl_xor(32) combines halves;
// lanes 0-31 store the full 256-col row as 32x16B full-line bursts.
__global__ __launch_bounds__(256) void aggregate_kernel(const unsigned short* __restrict__ featn,
                                                        const unsigned short* __restrict__ eperm,
                                                        const int* __restrict__ row_off,
                                                        const int* __restrict__ perm,
                                                        unsigned short* __restrict__ h_bf) {
    int node = blockIdx.x * 4 + (threadIdx.x >> 6);
    int lane = threadIdx.x & 63;
    if (node >= NN) return;
    int start = row_off[node];
    int end   = row_off[node + 1];

    int half = lane >> 5;
    int l    = lane & 31;
    bool isF = (l < 24);
    const unsigned short* fbase = featn + l * 8;          // + src*192
    const unsigned short* ebase = eperm + (l - 24) * 8;   // + pos*64

    float acc[8];
#pragma unroll
    for (int k = 0; k < 8; ++k) acc[k] = 0.f;

    for (int i = start + half; i < end; i += 8) {
        int idx[4]; float w[4]; int s[4];
#pragma unroll
        for (int j = 0; j < 4; ++j) {
            int ii = i + 2 * j;
            idx[j] = min(ii, end - 1);
            w[j] = (ii < end) ? 1.f : 0.f;
        }
#pragma unroll
        for (int j = 0; j < 4; ++j) s[j] = perm[idx[j]];
        bf16x8 u[4];
#pragma unroll
        for (int j = 0; j < 4; ++j) {
            const unsigned short* p = isF ? (fbase + (size_t)s[j] * 192)
                                          : (ebase + (size_t)idx[j] * 64);
            u[j] = *(const bf16x8*)p;
        }
#pragma unroll
        for (int j = 0; j < 4; ++j) {
#pragma unroll
            for (int k = 0; k < 8; ++k)
                acc[k] = fmaf(bf2f((unsigned short)u[j][k]), w[j], acc[k]);
        }
    }

    // combine the two halves (edge parity sums)
#pragma unroll
    for (int k = 0; k < 8; ++k) acc[k] += __shfl_xor(acc[k], 32);

    if (lane < 32) {
        u16x8 o;
#pragma unroll
        for (int k = 0; k < 8; ++k) o[k] = f2bf(acc[k]);
        *(u16x8*)(h_bf + (size_t)node * 256 + l * 8) = o;
    }
}

// -------- fallback path (ws too small): round-1 verified kernels -----------
__global__ __launch_bounds__(256) void fill_fb(const int* __restrict__ src,
                                               const int* __restrict__ dst,
                                               int* __restrict__ cursor,
                                               int2* __restrict__ perm2) {
    int e = blockIdx.x * 256 + threadIdx.x;
    if (e < NE) {
        int d = dst[e];
        int pos = atomicAdd(cursor + d, 1);
        perm2[pos] = make_int2(e, src[e]);
    }
}

__global__ __launch_bounds__(256) void aggregate_fb(const unsigned short* __restrict__ featn,
                                                    const float* __restrict__ edge_feat,
                                                    const int* __restrict__ row_off,
                                                    const int2* __restrict__ perm2,
                                                    unsigned short* __restrict__ h_bf) {
    int node = blockIdx.x * 4 + (threadIdx.x >> 6);
    int lane = threadIdx.x & 63;
    if (node >= NN) return;
    int start = row_off[node];
    int end   = row_off[node + 1];

    float4 acc = make_float4(0.f, 0.f, 0.f, 0.f);

    if (lane < 48) {
        const unsigned short* fb = featn + lane * 4;
        for (int i = start; i < end; i += 8) {
            int2 p[8];
#pragma unroll
            for (int j = 0; j < 8; ++j) p[j] = perm2[min(i + j, end - 1)];
            ushort4 u[8];
#pragma unroll
            for (int j = 0; j < 8; ++j)
                u[j] = *(const ushort4*)(fb + (size_t)p[j].y * 192);
#pragma unroll
            for (int j = 0; j < 8; ++j) {
                float w = (i + j < end) ? 1.f : 0.f;
                acc.x = fmaf(bf2f(u[j].x), w, acc.x);
                acc.y = fmaf(bf2f(u[j].y), w, acc.y);
                acc.z = fmaf(bf2f(u[j].z), w, acc.z);
                acc.w = fmaf(bf2f(u[j].w), w, acc.w);
            }
        }
    } else {
        const float* eb = edge_feat + (lane - 48) * 4;
        for (int i = start; i < end; i += 8) {
            int2 p[8];
#pragma unroll
            for (int j = 0; j < 8; ++j) p[j] = perm2[min(i + j, end - 1)];
            float4 v[8];
#pragma unroll
            for (int j = 0; j < 8; ++j)
                v[j] = *(const float4*)(eb + (size_t)p[j].x * 64);
#pragma unroll
            for (int j = 0; j < 8; ++j) {
                float w = (i + j < end) ? 1.f : 0.f;
                acc.x = fmaf(v[j].x, w, acc.x);
                acc.y = fmaf(v[j].y, w, acc.y);
                acc.z = fmaf(v[j].z, w, acc.z);
                acc.w = fmaf(v[j].w, w, acc.w);
            }
        }
    }

    ushort4 o;
    o.x = f2bf(acc.x); o.y = f2bf(acc.y);
    o.z = f2bf(acc.z); o.w = f2bf(acc.w);
    *(ushort4*)(h_bf + (size_t)node * 256 + lane * 4) = o;
}

// MFMA GEMM: out = (h_bf @ W) * rsqrt(max(in_deg,1))[:,None] + bias
// Block = 16 rows x 256 cols; 4 waves side-by-side on cols (64 each).
// C/D: row = (lane>>4)*4 + reg, col = lane&15   [guide §3, m89-verified]
__global__ __launch_bounds__(256) void gemm_mfma(const unsigned short* __restrict__ h_bf,
                                                 const unsigned short* __restrict__ wt_bf,
                                                 const float* __restrict__ bias,
                                                 const int* __restrict__ row_off,
                                                 float* __restrict__ out) {
    int wave = threadIdx.x >> 6;
    int lane = threadIdx.x & 63;
    int m16  = lane & 15;
    int quad = lane >> 4;
    int rbase = blockIdx.x * 16;
    int cbase = wave * 64;

    const unsigned short* arow = h_bf + (size_t)(rbase + m16) * 256 + quad * 8;
    const unsigned short* b0p = wt_bf + (size_t)(cbase +  0 + m16) * 256 + quad * 8;
    const unsigned short* b1p = wt_bf + (size_t)(cbase + 16 + m16) * 256 + quad * 8;
    const unsigned short* b2p = wt_bf + (size_t)(cbase + 32 + m16) * 256 + quad * 8;
    const unsigned short* b3p = wt_bf + (size_t)(cbase + 48 + m16) * 256 + quad * 8;

    f32x4 acc0 = {0.f, 0.f, 0.f, 0.f};
    f32x4 acc1 = {0.f, 0.f, 0.f, 0.f};
    f32x4 acc2 = {0.f, 0.f, 0.f, 0.f};
    f32x4 acc3 = {0.f, 0.f, 0.f, 0.f};

#pragma unroll
    for (int k0 = 0; k0 < 256; k0 += 32) {
        bf16x8 a  = *(const bf16x8*)(arow + k0);
        bf16x8 b0 = *(const bf16x8*)(b0p + k0);
        bf16x8 b1 = *(const bf16x8*)(b1p + k0);
        bf16x8 b2 = *(const bf16x8*)(b2p + k0);
        bf16x8 b3 = *(const bf16x8*)(b3p + k0);
        acc0 = __builtin_amdgcn_mfma_f32_16x16x32_bf16(a, b0, acc0, 0, 0, 0);
        acc1 = __builtin_amdgcn_mfma_f32_16x16x32_bf16(a, b1, acc1, 0, 0, 0);
        acc2 = __builtin_amdgcn_mfma_f32_16x16x32_bf16(a, b2, acc2, 0, 0, 0);
        acc3 = __builtin_amdgcn_mfma_f32_16x16x32_bf16(a, b3, acc3, 0, 0, 0);
    }

    // in-degree scales for this lane's 4 output rows
    int grow0 = rbase + quad * 4;
    float s[4];
    int ro_prev = row_off[grow0];
#pragma unroll
    for (int r = 0; r < 4; ++r) {
        int nx = row_off[grow0 + r + 1];
        s[r] = rsqrtf((float)max(nx - ro_prev, 1));
        ro_prev = nx;
    }

    float bv0 = bias[cbase +  0 + m16];
    float bv1 = bias[cbase + 16 + m16];
    float bv2 = bias[cbase + 32 + m16];
    float bv3 = bias[cbase + 48 + m16];

#pragma unroll
    for (int r = 0; r < 4; ++r) {
        size_t rowoff = (size_t)(grow0 + r) * DOUT;
        out[rowoff + cbase +  0 + m16] = acc0[r] * s[r] + bv0;
        out[rowoff + cbase + 16 + m16] = acc1[r] * s[r] + bv1;
        out[rowoff + cbase + 32 + m16] = acc2[r] * s[r] + bv2;
        out[rowoff + cbase + 48 + m16] = acc3[r] * s[r] + bv3;
    }
}

extern "C" void kernel_launch(void* const* d_in, const int* in_sizes, int n_in,
                              void* d_out, int out_size, void* d_ws, size_t ws_size,
                              hipStream_t stream) {
    const float* feat      = (const float*)d_in[0];
    const float* edge_feat = (const float*)d_in[1];
    const int*   src       = (const int*)d_in[2];
    const int*   dst       = (const int*)d_in[3];
    const float* W         = (const float*)d_in[4];
    const float* bias      = (const float*)d_in[5];
    float* out = (float*)d_out;

    // common big arrays (all 256B-aligned by construction)
    unsigned short* h_bf  = (unsigned short*)d_ws;            // NN*256 bf16
    unsigned short* wt_bf = h_bf + (size_t)NN * DIN;          // 256*256 bf16
    unsigned short* featn = wt_bf + 256 * 256;                // NN*192 bf16

    // big path layout: eperm directly after featn (256B-aligned)
    unsigned short* eperm = featn + (size_t)NN * 192;         // NE*64 bf16
    int*   perm_b     = (int*)(eperm + (size_t)NE * 64);      // NE int
    int*   row_off_b  = perm_b + NE;                          // NN+2
    float* odeg_inv_b = (float*)(row_off_b + NN + 2);         // NN
    int*   cursor_b   = (int*)(odeg_inv_b + NN);              // NN
    int*   bsum_b     = cursor_b + NN;                        // 256
    size_t need = (size_t)((char*)(bsum_b + 256) - (char*)d_ws);

    // fallback layout (round-1): meta after featn, perm2 after bsum
    int*   row_off_s  = (int*)(featn + (size_t)NN * 192);
    float* odeg_inv_s = (float*)(row_off_s + NN + 2);
    int*   cursor_s   = (int*)(odeg_inv_s + NN);
    int*   bsum_s     = cursor_s + NN;
    int2*  perm2      = (int2*)(bsum_s + 256);

    bool big_ws = (ws_size >= need);

    int*   row_off  = big_ws ? row_off_b  : row_off_s;
    float* odeg_inv = big_ws ? odeg_inv_b : odeg_inv_s;
    int*   cursor   = big_ws ? cursor_b   : cursor_s;
    int*   bsum     = big_ws ? bsum_b     : bsum_s;
    int*   in_cnt   = big_ws ? perm_b     : (int*)perm2;      // alias (early)
    int*   out_cnt  = in_cnt + NN;                            // alias (early)

    const int SCAN_BLOCKS = (NN + 255) / 256;   // 196

    zero_meta<<<(2 * NN + 255) / 256, 256, 0, stream>>>(in_cnt, 2 * NN);
    count_kernel<<<(NE + 255) / 256, 256, 0, stream>>>(src, dst, in_cnt, out_cnt);
    scan1<<<SCAN_BLOCKS, 256, 0, stream>>>(in_cnt, row_off, bsum);
    scan2<<<1, 256, 0, stream>>>(bsum, SCAN_BLOCKS);
    scan3<<<(NN + 256) / 256, 256, 0, stream>>>(row_off, cursor, odeg_inv, out_cnt, bsum);
    wconv<<<256, 256, 0, stream>>>(W, wt_bf);
    if (big_ws) {
        // fill BEFORE featconv so featn stays L3-resident for aggregate
        fill_kernel<<<NE / 16, 256, 0, stream>>>(src, dst, cursor, perm_b,
                                                 eperm, edge_feat);
        featconv<<<(NN + 3) / 4, 256, 0, stream>>>(feat, odeg_inv, featn);
        aggregate_kernel<<<(NN + 3) / 4, 256, 0, stream>>>(featn, eperm, row_off,
                                                           perm_b, h_bf);
    } else {
        featconv<<<(NN + 3) / 4, 256, 0, stream>>>(feat, odeg_inv, featn);
        fill_fb<<<(NE + 255) / 256, 256, 0, stream>>>(src, dst, cursor, perm2);
        aggregate_fb<<<(NN + 3) / 4, 256, 0, stream>>>(featn, edge_feat, row_off,
                                                       perm2, h_bf);
    }
    gemm_mfma<<<NN / 16, 256, 0, stream>>>(h_bf, wt_bf, bias, row_off, out);
}

// Round 6
// 536.936 us; speedup vs baseline: 1.1326x; 1.0184x over previous
//
#include <hip/hip_runtime.h>

// Problem constants (match setup_inputs)
#define NN 50000      // nodes
#define NE 800000     // edges
#define DIN 256       // 192 + 64
#define DOUT 256

#define LDS_STRIDE 264   // 256 + 8 bf16 pad: breaks row->same-bank degeneracy

typedef __attribute__((ext_vector_type(8))) short bf16x8;          // 8 bf16 = 4 VGPRs
typedef __attribute__((ext_vector_type(8))) unsigned short u16x8;  // 8 bf16 store
typedef __attribute__((ext_vector_type(4))) float f32x4;           // MFMA acc

__device__ __forceinline__ unsigned short f2bf(float x) {
    unsigned int u = __builtin_bit_cast(unsigned int, x);
    u += 0x7fffu + ((u >> 16) & 1u);        // round-to-nearest-even
    return (unsigned short)(u >> 16);
}
__device__ __forceinline__ float bf2f(unsigned short b) {
    return __builtin_bit_cast(float, ((unsigned int)b) << 16);
}

// ---------------------------------------------------------------------------
// ws layout, big path (~151.3 MB), ALL big arrays 256B-aligned:
//   h_bf     [NN*256]  bf16   (big path: unused; kept for fallback/layout)
//   wt_bf    [256*256] bf16
//   featn_bf [NN*192]  bf16
//   eperm    [NE*64]   bf16   (256B-aligned: pos*128 = full line)
//   perm     [NE]      int    (src id, CSR order; first 2*NN alias in/out_cnt)
//   row_off  [NN+2]    int
//   odeg_inv [NN]      float
//   cursor   [NN]      int
//   bsum     [256]     int
// Fallback path (small ws): round-1 layout, perm2[NE] int2 after bsum.
// ---------------------------------------------------------------------------

__global__ __launch_bounds__(256) void zero_meta(int* __restrict__ p, int n) {
    int i = blockIdx.x * 256 + threadIdx.x;
    if (i < n) p[i] = 0;
}

__global__ __launch_bounds__(256) void count_kernel(const int* __restrict__ src,
                                                    const int* __restrict__ dst,
                                                    int* __restrict__ in_cnt,
                                                    int* __restrict__ out_cnt) {
    int e = blockIdx.x * 256 + threadIdx.x;
    if (e < NE) {
        atomicAdd(in_cnt + dst[e], 1);
        atomicAdd(out_cnt + src[e], 1);
    }
}

__global__ __launch_bounds__(256) void scan1(const int* __restrict__ cnt,
                                             int* __restrict__ row_off,
                                             int* __restrict__ bsum) {
    __shared__ int tmp[256];
    int tid = threadIdx.x;
    int i = blockIdx.x * 256 + tid;
    int v = (i < NN) ? cnt[i] : 0;
    tmp[tid] = v;
    __syncthreads();
#pragma unroll
    for (int off = 1; off < 256; off <<= 1) {
        int t = (tid >= off) ? tmp[tid - off] : 0;
        __syncthreads();
        if (tid >= off) tmp[tid] += t;
        __syncthreads();
    }
    if (i < NN) row_off[i] = tmp[tid] - v;   // exclusive
    if (tid == 255) bsum[blockIdx.x] = tmp[255];
}

__global__ __launch_bounds__(256) void scan2(int* __restrict__ bsum, int nb) {
    __shared__ int tmp[256];
    int tid = threadIdx.x;
    int v = (tid < nb) ? bsum[tid] : 0;
    tmp[tid] = v;
    __syncthreads();
#pragma unroll
    for (int off = 1; off < 256; off <<= 1) {
        int t = (tid >= off) ? tmp[tid - off] : 0;
        __syncthreads();
        if (tid >= off) tmp[tid] += t;
        __syncthreads();
    }
    if (tid < nb) bsum[tid] = tmp[tid] - v;  // exclusive
}

// Finish row_off scan; seed cursor; fold in odeg_inv (out_cnt still live here).
__global__ __launch_bounds__(256) void scan3(int* __restrict__ row_off,
                                             int* __restrict__ cursor,
                                             float* __restrict__ odeg_inv,
                                             const int* __restrict__ out_cnt,
                                             const int* __restrict__ bsum) {
    int i = blockIdx.x * 256 + threadIdx.x;
    if (i < NN) {
        int v = row_off[i] + bsum[i >> 8];
        row_off[i] = v;
        cursor[i] = v;
        odeg_inv[i] = rsqrtf((float)max(out_cnt[i], 1));
    }
    if (i == NN) row_off[NN] = NE;
}

// W[k][n] fp32 -> wt[n][k] bf16
__global__ __launch_bounds__(256) void wconv(const float* __restrict__ W,
                                             unsigned short* __restrict__ wt) {
    int n = blockIdx.x, k = threadIdx.x;
    wt[n * 256 + k] = f2bf(W[k * 256 + n]);
}

// featn_bf[n][k] = bf16(feat[n][k] * odeg_inv[n]).
__global__ __launch_bounds__(256) void featconv(const float* __restrict__ feat,
                                                const float* __restrict__ odeg_inv,
                                                unsigned short* __restrict__ featn) {
    int node = blockIdx.x * 4 + (threadIdx.x >> 6);
    int lane = threadIdx.x & 63;
    if (node >= NN || lane >= 48) return;
    float s = odeg_inv[node];
    float4 v = *(const float4*)(feat + (size_t)node * 192 + lane * 4);
    ushort4 o;
    o.x = f2bf(v.x * s); o.y = f2bf(v.y * s);
    o.z = f2bf(v.z * s); o.w = f2bf(v.w * s);
    *(ushort4*)(featn + (size_t)node * 192 + lane * 4) = o;
}

// Wave-cooperative CSR fill: 16 lanes per edge.
// Per edge: read = 256B contiguous burst, write = ONE full 128B line.
__global__ __launch_bounds__(256) void fill_kernel(const int* __restrict__ src,
                                                   const int* __restrict__ dst,
                                                   int* __restrict__ cursor,
                                                   int* __restrict__ perm,
                                                   unsigned short* __restrict__ eperm,
                                                   const float* __restrict__ edge_feat) {
    int tid = threadIdx.x;
    int e   = blockIdx.x * 16 + (tid >> 4);   // 16 edges per block
    int sub = tid & 15;
    if (e >= NE) return;
    int pos = 0;
    if (sub == 0) {
        pos = atomicAdd(cursor + dst[e], 1);
        perm[pos] = src[e];
    }
    pos = __shfl(pos, 0, 16);                 // broadcast within 16-lane group
    float4 v = *(const float4*)(edge_feat + (size_t)e * 64 + sub * 4);
    ushort4 o;
    o.x = f2bf(v.x); o.y = f2bf(v.y); o.z = f2bf(v.z); o.w = f2bf(v.w);
    *(ushort4*)(eperm + (size_t)pos * 64 + sub * 4) = o;
}

// FUSED aggregate + GEMM. Block = 16 nodes (4 waves x 4 nodes), NN = 3125*16.
// Phase 1 (per wave, 4 nodes sequentially): v2 aggregate — 2 edges in flight
//   (half = lane>>5), l<24 gathers 16B of featn, l>=24 streams 16B of eperm;
//   __shfl_xor(32) combine; lanes 0-31 park the bf16 row in LDS (stride 264).
// Phase 2 (after one barrier): the round-4 MFMA tile, A-fragments from LDS,
//   B from wt_bf (L2-resident), epilogue in-degree scale + bias -> out.
__global__ __launch_bounds__(256) void agg_gemm(const unsigned short* __restrict__ featn,
                                                const unsigned short* __restrict__ eperm,
                                                const int* __restrict__ row_off,
                                                const int* __restrict__ perm,
                                                const unsigned short* __restrict__ wt_bf,
                                                const float* __restrict__ bias,
                                                float* __restrict__ out) {
    __shared__ unsigned short hlds[16 * LDS_STRIDE];

    int wave = threadIdx.x >> 6;
    int lane = threadIdx.x & 63;
    int rbase = blockIdx.x * 16;

    // ---- phase 1: aggregate 4 nodes for this wave ----
    int half = lane >> 5;
    int l    = lane & 31;
    bool isF = (l < 24);
    const unsigned short* fbase = featn + l * 8;          // + src*192
    const unsigned short* ebase = eperm + (l - 24) * 8;   // + pos*64

    for (int c = 0; c < 4; ++c) {
        int node = rbase + wave * 4 + c;
        int start = row_off[node];
        int end   = row_off[node + 1];

        float acc[8];
#pragma unroll
        for (int k = 0; k < 8; ++k) acc[k] = 0.f;

        for (int i = start + half; i < end; i += 8) {
            int idx[4]; float w[4]; int s[4];
#pragma unroll
            for (int j = 0; j < 4; ++j) {
                int ii = i + 2 * j;
                idx[j] = min(ii, end - 1);
                w[j] = (ii < end) ? 1.f : 0.f;
            }
#pragma unroll
            for (int j = 0; j < 4; ++j) s[j] = perm[idx[j]];
            bf16x8 u[4];
#pragma unroll
            for (int j = 0; j < 4; ++j) {
                const unsigned short* p = isF ? (fbase + (size_t)s[j] * 192)
                                              : (ebase + (size_t)idx[j] * 64);
                u[j] = *(const bf16x8*)p;
            }
#pragma unroll
            for (int j = 0; j < 4; ++j) {
#pragma unroll
                for (int k = 0; k < 8; ++k)
                    acc[k] = fmaf(bf2f((unsigned short)u[j][k]), w[j], acc[k]);
            }
        }

#pragma unroll
        for (int k = 0; k < 8; ++k) acc[k] += __shfl_xor(acc[k], 32);

        if (lane < 32) {
            u16x8 o;
#pragma unroll
            for (int k = 0; k < 8; ++k) o[k] = f2bf(acc[k]);
            *(u16x8*)(hlds + (wave * 4 + c) * LDS_STRIDE + l * 8) = o;
        }
    }

    __syncthreads();

    // ---- phase 2: 16x256 GEMM tile, A from LDS ----
    int m16  = lane & 15;
    int quad = lane >> 4;
    int cbase = wave * 64;

    const unsigned short* arow = hlds + m16 * LDS_STRIDE + quad * 8;
    const unsigned short* b0p = wt_bf + (size_t)(cbase +  0 + m16) * 256 + quad * 8;
    const unsigned short* b1p = wt_bf + (size_t)(cbase + 16 + m16) * 256 + quad * 8;
    const unsigned short* b2p = wt_bf + (size_t)(cbase + 32 + m16) * 256 + quad * 8;
    const unsigned short* b3p = wt_bf + (size_t)(cbase + 48 + m16) * 256 + quad * 8;

    f32x4 acc0 = {0.f, 0.f, 0.f, 0.f};
    f32x4 acc1 = {0.f, 0.f, 0.f, 0.f};
    f32x4 acc2 = {0.f, 0.f, 0.f, 0.f};
    f32x4 acc3 = {0.f, 0.f, 0.f, 0.f};

#pragma unroll
    for (int k0 = 0; k0 < 256; k0 += 32) {
        bf16x8 a  = *(const bf16x8*)(arow + k0);
        bf16x8 b0 = *(const bf16x8*)(b0p + k0);
        bf16x8 b1 = *(const bf16x8*)(b1p + k0);
        bf16x8 b2 = *(const bf16x8*)(b2p + k0);
        bf16x8 b3 = *(const bf16x8*)(b3p + k0);
        acc0 = __builtin_amdgcn_mfma_f32_16x16x32_bf16(a, b0, acc0, 0, 0, 0);
        acc1 = __builtin_amdgcn_mfma_f32_16x16x32_bf16(a, b1, acc1, 0, 0, 0);
        acc2 = __builtin_amdgcn_mfma_f32_16x16x32_bf16(a, b2, acc2, 0, 0, 0);
        acc3 = __builtin_amdgcn_mfma_f32_16x16x32_bf16(a, b3, acc3, 0, 0, 0);
    }

    // in-degree scales for this lane's 4 output rows
    int grow0 = rbase + quad * 4;
    float s[4];
    int ro_prev = row_off[grow0];
#pragma unroll
    for (int r = 0; r < 4; ++r) {
        int nx = row_off[grow0 + r + 1];
        s[r] = rsqrtf((float)max(nx - ro_prev, 1));
        ro_prev = nx;
    }

    float bv0 = bias[cbase +  0 + m16];
    float bv1 = bias[cbase + 16 + m16];
    float bv2 = bias[cbase + 32 + m16];
    float bv3 = bias[cbase + 48 + m16];

#pragma unroll
    for (int r = 0; r < 4; ++r) {
        size_t rowoff = (size_t)(grow0 + r) * DOUT;
        out[rowoff + cbase +  0 + m16] = acc0[r] * s[r] + bv0;
        out[rowoff + cbase + 16 + m16] = acc1[r] * s[r] + bv1;
        out[rowoff + cbase + 32 + m16] = acc2[r] * s[r] + bv2;
        out[rowoff + cbase + 48 + m16] = acc3[r] * s[r] + bv3;
    }
}

// -------- fallback path (ws too small): round-1 verified kernels -----------
__global__ __launch_bounds__(256) void fill_fb(const int* __restrict__ src,
                                               const int* __restrict__ dst,
                                               int* __restrict__ cursor,
                                               int2* __restrict__ perm2) {
    int e = blockIdx.x * 256 + threadIdx.x;
    if (e < NE) {
        int d = dst[e];
        int pos = atomicAdd(cursor + d, 1);
        perm2[pos] = make_int2(e, src[e]);
    }
}

__global__ __launch_bounds__(256) void aggregate_fb(const unsigned short* __restrict__ featn,
                                                    const float* __restrict__ edge_feat,
                                                    const int* __restrict__ row_off,
                                                    const int2* __restrict__ perm2,
                                                    unsigned short* __restrict__ h_bf) {
    int node = blockIdx.x * 4 + (threadIdx.x >> 6);
    int lane = threadIdx.x & 63;
    if (node >= NN) return;
    int start = row_off[node];
    int end   = row_off[node + 1];

    float4 acc = make_float4(0.f, 0.f, 0.f, 0.f);

    if (lane < 48) {
        const unsigned short* fb = featn + lane * 4;
        for (int i = start; i < end; i += 8) {
            int2 p[8];
#pragma unroll
            for (int j = 0; j < 8; ++j) p[j] = perm2[min(i + j, end - 1)];
            ushort4 u[8];
#pragma unroll
            for (int j = 0; j < 8; ++j)
                u[j] = *(const ushort4*)(fb + (size_t)p[j].y * 192);
#pragma unroll
            for (int j = 0; j < 8; ++j) {
                float w = (i + j < end) ? 1.f : 0.f;
                acc.x = fmaf(bf2f(u[j].x), w, acc.x);
                acc.y = fmaf(bf2f(u[j].y), w, acc.y);
                acc.z = fmaf(bf2f(u[j].z), w, acc.z);
                acc.w = fmaf(bf2f(u[j].w), w, acc.w);
            }
        }
    } else {
        const float* eb = edge_feat + (lane - 48) * 4;
        for (int i = start; i < end; i += 8) {
            int2 p[8];
#pragma unroll
            for (int j = 0; j < 8; ++j) p[j] = perm2[min(i + j, end - 1)];
            float4 v[8];
#pragma unroll
            for (int j = 0; j < 8; ++j)
                v[j] = *(const float4*)(eb + (size_t)p[j].x * 64);
#pragma unroll
            for (int j = 0; j < 8; ++j) {
                float w = (i + j < end) ? 1.f : 0.f;
                acc.x = fmaf(v[j].x, w, acc.x);
                acc.y = fmaf(v[j].y, w, acc.y);
                acc.z = fmaf(v[j].z, w, acc.z);
                acc.w = fmaf(v[j].w, w, acc.w);
            }
        }
    }

    ushort4 o;
    o.x = f2bf(acc.x); o.y = f2bf(acc.y);
    o.z = f2bf(acc.z); o.w = f2bf(acc.w);
    *(ushort4*)(h_bf + (size_t)node * 256 + lane * 4) = o;
}

// standalone GEMM (fallback path only)
__global__ __launch_bounds__(256) void gemm_mfma(const unsigned short* __restrict__ h_bf,
                                                 const unsigned short* __restrict__ wt_bf,
                                                 const float* __restrict__ bias,
                                                 const int* __restrict__ row_off,
                                                 float* __restrict__ out) {
    int wave = threadIdx.x >> 6;
    int lane = threadIdx.x & 63;
    int m16  = lane & 15;
    int quad = lane >> 4;
    int rbase = blockIdx.x * 16;
    int cbase = wave * 64;

    const unsigned short* arow = h_bf + (size_t)(rbase + m16) * 256 + quad * 8;
    const unsigned short* b0p = wt_bf + (size_t)(cbase +  0 + m16) * 256 + quad * 8;
    const unsigned short* b1p = wt_bf + (size_t)(cbase + 16 + m16) * 256 + quad * 8;
    const unsigned short* b2p = wt_bf + (size_t)(cbase + 32 + m16) * 256 + quad * 8;
    const unsigned short* b3p = wt_bf + (size_t)(cbase + 48 + m16) * 256 + quad * 8;

    f32x4 acc0 = {0.f, 0.f, 0.f, 0.f};
    f32x4 acc1 = {0.f, 0.f, 0.f, 0.f};
    f32x4 acc2 = {0.f, 0.f, 0.f, 0.f};
    f32x4 acc3 = {0.f, 0.f, 0.f, 0.f};

#pragma unroll
    for (int k0 = 0; k0 < 256; k0 += 32) {
        bf16x8 a  = *(const bf16x8*)(arow + k0);
        bf16x8 b0 = *(const bf16x8*)(b0p + k0);
        bf16x8 b1 = *(const bf16x8*)(b1p + k0);
        bf16x8 b2 = *(const bf16x8*)(b2p + k0);
        bf16x8 b3 = *(const bf16x8*)(b3p + k0);
        acc0 = __builtin_amdgcn_mfma_f32_16x16x32_bf16(a, b0, acc0, 0, 0, 0);
        acc1 = __builtin_amdgcn_mfma_f32_16x16x32_bf16(a, b1, acc1, 0, 0, 0);
        acc2 = __builtin_amdgcn_mfma_f32_16x16x32_bf16(a, b2, acc2, 0, 0, 0);
        acc3 = __builtin_amdgcn_mfma_f32_16x16x32_bf16(a, b3, acc3, 0, 0, 0);
    }

    int grow0 = rbase + quad * 4;
    float s[4];
    int ro_prev = row_off[grow0];
#pragma unroll
    for (int r = 0; r < 4; ++r) {
        int nx = row_off[grow0 + r + 1];
        s[r] = rsqrtf((float)max(nx - ro_prev, 1));
        ro_prev = nx;
    }

    float bv0 = bias[cbase +  0 + m16];
    float bv1 = bias[cbase + 16 + m16];
    float bv2 = bias[cbase + 32 + m16];
    float bv3 = bias[cbase + 48 + m16];

#pragma unroll
    for (int r = 0; r < 4; ++r) {
        size_t rowoff = (size_t)(grow0 + r) * DOUT;
        out[rowoff + cbase +  0 + m16] = acc0[r] * s[r] + bv0;
        out[rowoff + cbase + 16 + m16] = acc1[r] * s[r] + bv1;
        out[rowoff + cbase + 32 + m16] = acc2[r] * s[r] + bv2;
        out[rowoff + cbase + 48 + m16] = acc3[r] * s[r] + bv3;
    }
}

extern "C" void kernel_launch(void* const* d_in, const int* in_sizes, int n_in,
                              void* d_out, int out_size, void* d_ws, size_t ws_size,
                              hipStream_t stream) {
    const float* feat      = (const float*)d_in[0];
    const float* edge_feat = (const float*)d_in[1];
    const int*   src       = (const int*)d_in[2];
    const int*   dst       = (const int*)d_in[3];
    const float* W         = (const float*)d_in[4];
    const float* bias      = (const float*)d_in[5];
    float* out = (float*)d_out;

    // common big arrays (all 256B-aligned by construction)
    unsigned short* h_bf  = (unsigned short*)d_ws;            // NN*256 bf16
    unsigned short* wt_bf = h_bf + (size_t)NN * DIN;          // 256*256 bf16
    unsigned short* featn = wt_bf + 256 * 256;                // NN*192 bf16

    // big path layout: eperm directly after featn (256B-aligned)
    unsigned short* eperm = featn + (size_t)NN * 192;         // NE*64 bf16
    int*   perm_b     = (int*)(eperm + (size_t)NE * 64);      // NE int
    int*   row_off_b  = perm_b + NE;                          // NN+2
    float* odeg_inv_b = (float*)(row_off_b + NN + 2);         // NN
    int*   cursor_b   = (int*)(odeg_inv_b + NN);              // NN
    int*   bsum_b     = cursor_b + NN;                        // 256
    size_t need = (size_t)((char*)(bsum_b + 256) - (char*)d_ws);

    // fallback layout (round-1): meta after featn, perm2 after bsum
    int*   row_off_s  = (int*)(featn + (size_t)NN * 192);
    float* odeg_inv_s = (float*)(row_off_s + NN + 2);
    int*   cursor_s   = (int*)(odeg_inv_s + NN);
    int*   bsum_s     = cursor_s + NN;
    int2*  perm2      = (int2*)(bsum_s + 256);

    bool big_ws = (ws_size >= need);

    int*   row_off  = big_ws ? row_off_b  : row_off_s;
    float* odeg_inv = big_ws ? odeg_inv_b : odeg_inv_s;
    int*   cursor   = big_ws ? cursor_b   : cursor_s;
    int*   bsum     = big_ws ? bsum_b     : bsum_s;
    int*   in_cnt   = big_ws ? perm_b     : (int*)perm2;      // alias (early)
    int*   out_cnt  = in_cnt + NN;                            // alias (early)

    const int SCAN_BLOCKS = (NN + 255) / 256;   // 196

    zero_meta<<<(2 * NN + 255) / 256, 256, 0, stream>>>(in_cnt, 2 * NN);
    count_kernel<<<(NE + 255) / 256, 256, 0, stream>>>(src, dst, in_cnt, out_cnt);
    scan1<<<SCAN_BLOCKS, 256, 0, stream>>>(in_cnt, row_off, bsum);
    scan2<<<1, 256, 0, stream>>>(bsum, SCAN_BLOCKS);
    scan3<<<(NN + 256) / 256, 256, 0, stream>>>(row_off, cursor, odeg_inv, out_cnt, bsum);
    wconv<<<256, 256, 0, stream>>>(W, wt_bf);
    if (big_ws) {
        // fill BEFORE featconv so featn stays L3-resident for agg_gemm
        fill_kernel<<<NE / 16, 256, 0, stream>>>(src, dst, cursor, perm_b,
                                                 eperm, edge_feat);
        featconv<<<(NN + 3) / 4, 256, 0, stream>>>(feat, odeg_inv, featn);
        agg_gemm<<<NN / 16, 256, 0, stream>>>(featn, eperm, row_off, perm_b,
                                              wt_bf, bias, out);
    } else {
        featconv<<<(NN + 3) / 4, 256, 0, stream>>>(feat, odeg_inv, featn);
        fill_fb<<<(NE + 255) / 256, 256, 0, stream>>>(src, dst, cursor, perm2);
        aggregate_fb<<<(NN + 3) / 4, 256, 0, stream>>>(featn, edge_feat, row_off,
                                                       perm2, h_bf);
        gemm_mfma<<<NN / 16, 256, 0, stream>>>(h_bf, wt_bf, bias, row_off, out);
    }
}

// Round 7
// 536.020 us; speedup vs baseline: 1.1346x; 1.0017x over previous
//
#include <hip/hip_runtime.h>

// Problem constants (match setup_inputs)
#define NN 50000      // nodes
#define NE 800000     // edges
#define DIN 256       // 192 + 64
#define DOUT 256

#define LDS_STRIDE 264   // 256 + 8 bf16 pad: phase-2 A-reads land 2-way (free)

typedef __attribute__((ext_vector_type(8))) short bf16x8;          // 8 bf16 = 4 VGPRs
typedef __attribute__((ext_vector_type(8))) unsigned short u16x8;  // 8 bf16 store
typedef __attribute__((ext_vector_type(4))) float f32x4;           // MFMA acc

__device__ __forceinline__ unsigned short f2bf(float x) {
    unsigned int u = __builtin_bit_cast(unsigned int, x);
    u += 0x7fffu + ((u >> 16) & 1u);        // round-to-nearest-even
    return (unsigned short)(u >> 16);
}
__device__ __forceinline__ float bf2f(unsigned short b) {
    return __builtin_bit_cast(float, ((unsigned int)b) << 16);
}

// ---------------------------------------------------------------------------
// ws layout, big path (~151.3 MB), ALL big arrays 256B-aligned:
//   h_bf     [NN*256]  bf16   (big path: unused; kept for fallback/layout)
//   wt_bf    [256*256] bf16
//   featn_bf [NN*192]  bf16
//   eperm    [NE*64]   bf16   (256B-aligned: pos*128 = full line)
//   perm     [NE]      int    (src id, CSR order; first 2*NN alias in/out_cnt)
//   row_off  [NN+2]    int
//   odeg_inv [NN]      float
//   cursor   [NN]      int
//   bsum     [256]     int
// Fallback path (small ws): round-1 layout, perm2[NE] int2 after bsum.
// ---------------------------------------------------------------------------

__global__ __launch_bounds__(256) void zero_meta(int* __restrict__ p, int n) {
    int i = blockIdx.x * 256 + threadIdx.x;
    if (i < n) p[i] = 0;
}

__global__ __launch_bounds__(256) void count_kernel(const int* __restrict__ src,
                                                    const int* __restrict__ dst,
                                                    int* __restrict__ in_cnt,
                                                    int* __restrict__ out_cnt) {
    int e = blockIdx.x * 256 + threadIdx.x;
    if (e < NE) {
        atomicAdd(in_cnt + dst[e], 1);
        atomicAdd(out_cnt + src[e], 1);
    }
}

__global__ __launch_bounds__(256) void scan1(const int* __restrict__ cnt,
                                             int* __restrict__ row_off,
                                             int* __restrict__ bsum) {
    __shared__ int tmp[256];
    int tid = threadIdx.x;
    int i = blockIdx.x * 256 + tid;
    int v = (i < NN) ? cnt[i] : 0;
    tmp[tid] = v;
    __syncthreads();
#pragma unroll
    for (int off = 1; off < 256; off <<= 1) {
        int t = (tid >= off) ? tmp[tid - off] : 0;
        __syncthreads();
        if (tid >= off) tmp[tid] += t;
        __syncthreads();
    }
    if (i < NN) row_off[i] = tmp[tid] - v;   // exclusive
    if (tid == 255) bsum[blockIdx.x] = tmp[255];
}

__global__ __launch_bounds__(256) void scan2(int* __restrict__ bsum, int nb) {
    __shared__ int tmp[256];
    int tid = threadIdx.x;
    int v = (tid < nb) ? bsum[tid] : 0;
    tmp[tid] = v;
    __syncthreads();
#pragma unroll
    for (int off = 1; off < 256; off <<= 1) {
        int t = (tid >= off) ? tmp[tid - off] : 0;
        __syncthreads();
        if (tid >= off) tmp[tid] += t;
        __syncthreads();
    }
    if (tid < nb) bsum[tid] = tmp[tid] - v;  // exclusive
}

// Finish row_off scan; seed cursor; fold in odeg_inv (out_cnt still live here).
__global__ __launch_bounds__(256) void scan3(int* __restrict__ row_off,
                                             int* __restrict__ cursor,
                                             float* __restrict__ odeg_inv,
                                             const int* __restrict__ out_cnt,
                                             const int* __restrict__ bsum) {
    int i = blockIdx.x * 256 + threadIdx.x;
    if (i < NN) {
        int v = row_off[i] + bsum[i >> 8];
        row_off[i] = v;
        cursor[i] = v;
        odeg_inv[i] = rsqrtf((float)max(out_cnt[i], 1));
    }
    if (i == NN) row_off[NN] = NE;
}

// W[k][n] fp32 -> wt[n][k] bf16
__global__ __launch_bounds__(256) void wconv(const float* __restrict__ W,
                                             unsigned short* __restrict__ wt) {
    int n = blockIdx.x, k = threadIdx.x;
    wt[n * 256 + k] = f2bf(W[k * 256 + n]);
}

// featn_bf[n][k] = bf16(feat[n][k] * odeg_inv[n]).
__global__ __launch_bounds__(256) void featconv(const float* __restrict__ feat,
                                                const float* __restrict__ odeg_inv,
                                                unsigned short* __restrict__ featn) {
    int node = blockIdx.x * 4 + (threadIdx.x >> 6);
    int lane = threadIdx.x & 63;
    if (node >= NN || lane >= 48) return;
    float s = odeg_inv[node];
    float4 v = *(const float4*)(feat + (size_t)node * 192 + lane * 4);
    ushort4 o;
    o.x = f2bf(v.x * s); o.y = f2bf(v.y * s);
    o.z = f2bf(v.z * s); o.w = f2bf(v.w * s);
    *(ushort4*)(featn + (size_t)node * 192 + lane * 4) = o;
}

// Wave-cooperative CSR fill: 16 lanes per edge.
// Per edge: read = 256B contiguous burst, write = ONE full 128B line.
__global__ __launch_bounds__(256) void fill_kernel(const int* __restrict__ src,
                                                   const int* __restrict__ dst,
                                                   int* __restrict__ cursor,
                                                   int* __restrict__ perm,
                                                   unsigned short* __restrict__ eperm,
                                                   const float* __restrict__ edge_feat) {
    int tid = threadIdx.x;
    int e   = blockIdx.x * 16 + (tid >> 4);   // 16 edges per block
    int sub = tid & 15;
    if (e >= NE) return;
    int pos = 0;
    if (sub == 0) {
        pos = atomicAdd(cursor + dst[e], 1);
        perm[pos] = src[e];
    }
    pos = __shfl(pos, 0, 16);                 // broadcast within 16-lane group
    float4 v = *(const float4*)(edge_feat + (size_t)e * 64 + sub * 4);
    ushort4 o;
    o.x = f2bf(v.x); o.y = f2bf(v.y); o.z = f2bf(v.z); o.w = f2bf(v.w);
    *(ushort4*)(eperm + (size_t)pos * 64 + sub * 4) = o;
}

// FUSED aggregate + GEMM. Block = 16 nodes (4 waves x 4 nodes), NN = 3125*16.
// Phase 1 v3: the wave's 4 nodes run CONCURRENTLY (acc[4][8], static idx).
//   Per step each lane issues 2 edges/node x 4 nodes = 8 independent gathers
//   in flight; no per-node pipeline drain (mean degree 16 => ~4-6 steps).
//   half = lane>>5 covers edge parity; l<24 feat part, l>=24 eperm part.
//   Dud edges (past end) clamp in-range and get w=0 (no extra bytes).
// Phase 2 (one barrier): MFMA tile, A from LDS, B from wt_bf (L2-resident).
__global__ __launch_bounds__(256) void agg_gemm(const unsigned short* __restrict__ featn,
                                                const unsigned short* __restrict__ eperm,
                                                const int* __restrict__ row_off,
                                                const int* __restrict__ perm,
                                                const unsigned short* __restrict__ wt_bf,
                                                const float* __restrict__ bias,
                                                float* __restrict__ out) {
    __shared__ unsigned short hlds[16 * LDS_STRIDE];

    int wave = threadIdx.x >> 6;
    int lane = threadIdx.x & 63;
    int rbase = blockIdx.x * 16;

    // ---- phase 1: aggregate 4 nodes concurrently ----
    int half = lane >> 5;
    int l    = lane & 31;
    bool isF = (l < 24);
    const unsigned short* fbase = featn + l * 8;          // + src*192
    const unsigned short* ebase = eperm + (l - 24) * 8;   // + pos*64

    int pos[4], end4[4];
    int nsteps = 0;
#pragma unroll
    for (int c = 0; c < 4; ++c) {
        int node = rbase + wave * 4 + c;
        int st = row_off[node];
        end4[c] = row_off[node + 1];
        pos[c] = st + half;
        int deg = end4[c] - st;
        nsteps = max(nsteps, (deg + 3) >> 2);   // ceil(deg/4), wave-uniform
    }

    float acc0[8], acc1[8], acc2[8], acc3[8];
#pragma unroll
    for (int k = 0; k < 8; ++k) { acc0[k] = 0.f; acc1[k] = 0.f; acc2[k] = 0.f; acc3[k] = 0.f; }

    for (int step = 0; step < nsteps; ++step) {
        int idx[8]; float w[8];
#pragma unroll
        for (int c = 0; c < 4; ++c) {
#pragma unroll
            for (int j = 0; j < 2; ++j) {
                int ii = pos[c] + 2 * j;
                int t = min(ii, end4[c] - 1);
                t = max(t, 0);                       // deg==0 safety
                idx[c * 2 + j] = t;
                w[c * 2 + j] = (ii < end4[c]) ? 1.f : 0.f;
            }
        }
        int s[8];
#pragma unroll
        for (int m = 0; m < 8; ++m) s[m] = perm[idx[m]];
        bf16x8 u[8];
#pragma unroll
        for (int m = 0; m < 8; ++m) {
            const unsigned short* p = isF ? (fbase + (size_t)s[m] * 192)
                                          : (ebase + (size_t)idx[m] * 64);
            u[m] = *(const bf16x8*)p;
        }
#pragma unroll
        for (int j = 0; j < 2; ++j) {
#pragma unroll
            for (int k = 0; k < 8; ++k) {
                acc0[k] = fmaf(bf2f((unsigned short)u[0 + j][k]), w[0 + j], acc0[k]);
                acc1[k] = fmaf(bf2f((unsigned short)u[2 + j][k]), w[2 + j], acc1[k]);
                acc2[k] = fmaf(bf2f((unsigned short)u[4 + j][k]), w[4 + j], acc2[k]);
                acc3[k] = fmaf(bf2f((unsigned short)u[6 + j][k]), w[6 + j], acc3[k]);
            }
        }
#pragma unroll
        for (int c = 0; c < 4; ++c) pos[c] += 4;
    }

    // combine halves and park rows in LDS
#pragma unroll
    for (int k = 0; k < 8; ++k) {
        acc0[k] += __shfl_xor(acc0[k], 32);
        acc1[k] += __shfl_xor(acc1[k], 32);
        acc2[k] += __shfl_xor(acc2[k], 32);
        acc3[k] += __shfl_xor(acc3[k], 32);
    }
    if (lane < 32) {
        u16x8 o0, o1, o2, o3;
#pragma unroll
        for (int k = 0; k < 8; ++k) {
            o0[k] = f2bf(acc0[k]); o1[k] = f2bf(acc1[k]);
            o2[k] = f2bf(acc2[k]); o3[k] = f2bf(acc3[k]);
        }
        unsigned short* hb = hlds + wave * 4 * LDS_STRIDE + l * 8;
        *(u16x8*)(hb + 0 * LDS_STRIDE) = o0;
        *(u16x8*)(hb + 1 * LDS_STRIDE) = o1;
        *(u16x8*)(hb + 2 * LDS_STRIDE) = o2;
        *(u16x8*)(hb + 3 * LDS_STRIDE) = o3;
    }

    __syncthreads();

    // ---- phase 2: 16x256 GEMM tile, A from LDS ----
    int m16  = lane & 15;
    int quad = lane >> 4;
    int cbase = wave * 64;

    const unsigned short* arow = hlds + m16 * LDS_STRIDE + quad * 8;
    const unsigned short* b0p = wt_bf + (size_t)(cbase +  0 + m16) * 256 + quad * 8;
    const unsigned short* b1p = wt_bf + (size_t)(cbase + 16 + m16) * 256 + quad * 8;
    const unsigned short* b2p = wt_bf + (size_t)(cbase + 32 + m16) * 256 + quad * 8;
    const unsigned short* b3p = wt_bf + (size_t)(cbase + 48 + m16) * 256 + quad * 8;

    f32x4 acc0v = {0.f, 0.f, 0.f, 0.f};
    f32x4 acc1v = {0.f, 0.f, 0.f, 0.f};
    f32x4 acc2v = {0.f, 0.f, 0.f, 0.f};
    f32x4 acc3v = {0.f, 0.f, 0.f, 0.f};

#pragma unroll
    for (int k0 = 0; k0 < 256; k0 += 32) {
        bf16x8 a  = *(const bf16x8*)(arow + k0);
        bf16x8 b0 = *(const bf16x8*)(b0p + k0);
        bf16x8 b1 = *(const bf16x8*)(b1p + k0);
        bf16x8 b2 = *(const bf16x8*)(b2p + k0);
        bf16x8 b3 = *(const bf16x8*)(b3p + k0);
        acc0v = __builtin_amdgcn_mfma_f32_16x16x32_bf16(a, b0, acc0v, 0, 0, 0);
        acc1v = __builtin_amdgcn_mfma_f32_16x16x32_bf16(a, b1, acc1v, 0, 0, 0);
        acc2v = __builtin_amdgcn_mfma_f32_16x16x32_bf16(a, b2, acc2v, 0, 0, 0);
        acc3v = __builtin_amdgcn_mfma_f32_16x16x32_bf16(a, b3, acc3v, 0, 0, 0);
    }

    // in-degree scales for this lane's 4 output rows
    int grow0 = rbase + quad * 4;
    float s4[4];
    int ro_prev = row_off[grow0];
#pragma unroll
    for (int r = 0; r < 4; ++r) {
        int nx = row_off[grow0 + r + 1];
        s4[r] = rsqrtf((float)max(nx - ro_prev, 1));
        ro_prev = nx;
    }

    float bv0 = bias[cbase +  0 + m16];
    float bv1 = bias[cbase + 16 + m16];
    float bv2 = bias[cbase + 32 + m16];
    float bv3 = bias[cbase + 48 + m16];

#pragma unroll
    for (int r = 0; r < 4; ++r) {
        size_t rowoff = (size_t)(grow0 + r) * DOUT;
        out[rowoff + cbase +  0 + m16] = acc0v[r] * s4[r] + bv0;
        out[rowoff + cbase + 16 + m16] = acc1v[r] * s4[r] + bv1;
        out[rowoff + cbase + 32 + m16] = acc2v[r] * s4[r] + bv2;
        out[rowoff + cbase + 48 + m16] = acc3v[r] * s4[r] + bv3;
    }
}

// -------- fallback path (ws too small): round-1 verified kernels -----------
__global__ __launch_bounds__(256) void fill_fb(const int* __restrict__ src,
                                               const int* __restrict__ dst,
                                               int* __restrict__ cursor,
                                               int2* __restrict__ perm2) {
    int e = blockIdx.x * 256 + threadIdx.x;
    if (e < NE) {
        int d = dst[e];
        int pos = atomicAdd(cursor + d, 1);
        perm2[pos] = make_int2(e, src[e]);
    }
}

__global__ __launch_bounds__(256) void aggregate_fb(const unsigned short* __restrict__ featn,
                                                    const float* __restrict__ edge_feat,
                                                    const int* __restrict__ row_off,
                                                    const int2* __restrict__ perm2,
                                                    unsigned short* __restrict__ h_bf) {
    int node = blockIdx.x * 4 + (threadIdx.x >> 6);
    int lane = threadIdx.x & 63;
    if (node >= NN) return;
    int start = row_off[node];
    int end   = row_off[node + 1];

    float4 acc = make_float4(0.f, 0.f, 0.f, 0.f);

    if (lane < 48) {
        const unsigned short* fb = featn + lane * 4;
        for (int i = start; i < end; i += 8) {
            int2 p[8];
#pragma unroll
            for (int j = 0; j < 8; ++j) p[j] = perm2[min(i + j, end - 1)];
            ushort4 u[8];
#pragma unroll
            for (int j = 0; j < 8; ++j)
                u[j] = *(const ushort4*)(fb + (size_t)p[j].y * 192);
#pragma unroll
            for (int j = 0; j < 8; ++j) {
                float w = (i + j < end) ? 1.f : 0.f;
                acc.x = fmaf(bf2f(u[j].x), w, acc.x);
                acc.y = fmaf(bf2f(u[j].y), w, acc.y);
                acc.z = fmaf(bf2f(u[j].z), w, acc.z);
                acc.w = fmaf(bf2f(u[j].w), w, acc.w);
            }
        }
    } else {
        const float* eb = edge_feat + (lane - 48) * 4;
        for (int i = start; i < end; i += 8) {
            int2 p[8];
#pragma unroll
            for (int j = 0; j < 8; ++j) p[j] = perm2[min(i + j, end - 1)];
            float4 v[8];
#pragma unroll
            for (int j = 0; j < 8; ++j)
                v[j] = *(const float4*)(eb + (size_t)p[j].x * 64);
#pragma unroll
            for (int j = 0; j < 8; ++j) {
                float w = (i + j < end) ? 1.f : 0.f;
                acc.x = fmaf(v[j].x, w, acc.x);
                acc.y = fmaf(v[j].y, w, acc.y);
                acc.z = fmaf(v[j].z, w, acc.z);
                acc.w = fmaf(v[j].w, w, acc.w);
            }
        }
    }

    ushort4 o;
    o.x = f2bf(acc.x); o.y = f2bf(acc.y);
    o.z = f2bf(acc.z); o.w = f2bf(acc.w);
    *(ushort4*)(h_bf + (size_t)node * 256 + lane * 4) = o;
}

// standalone GEMM (fallback path only)
__global__ __launch_bounds__(256) void gemm_mfma(const unsigned short* __restrict__ h_bf,
                                                 const unsigned short* __restrict__ wt_bf,
                                                 const float* __restrict__ bias,
                                                 const int* __restrict__ row_off,
                                                 float* __restrict__ out) {
    int wave = threadIdx.x >> 6;
    int lane = threadIdx.x & 63;
    int m16  = lane & 15;
    int quad = lane >> 4;
    int rbase = blockIdx.x * 16;
    int cbase = wave * 64;

    const unsigned short* arow = h_bf + (size_t)(rbase + m16) * 256 + quad * 8;
    const unsigned short* b0p = wt_bf + (size_t)(cbase +  0 + m16) * 256 + quad * 8;
    const unsigned short* b1p = wt_bf + (size_t)(cbase + 16 + m16) * 256 + quad * 8;
    const unsigned short* b2p = wt_bf + (size_t)(cbase + 32 + m16) * 256 + quad * 8;
    const unsigned short* b3p = wt_bf + (size_t)(cbase + 48 + m16) * 256 + quad * 8;

    f32x4 acc0 = {0.f, 0.f, 0.f, 0.f};
    f32x4 acc1 = {0.f, 0.f, 0.f, 0.f};
    f32x4 acc2 = {0.f, 0.f, 0.f, 0.f};
    f32x4 acc3 = {0.f, 0.f, 0.f, 0.f};

#pragma unroll
    for (int k0 = 0; k0 < 256; k0 += 32) {
        bf16x8 a  = *(const bf16x8*)(arow + k0);
        bf16x8 b0 = *(const bf16x8*)(b0p + k0);
        bf16x8 b1 = *(const bf16x8*)(b1p + k0);
        bf16x8 b2 = *(const bf16x8*)(b2p + k0);
        bf16x8 b3 = *(const bf16x8*)(b3p + k0);
        acc0 = __builtin_amdgcn_mfma_f32_16x16x32_bf16(a, b0, acc0, 0, 0, 0);
        acc1 = __builtin_amdgcn_mfma_f32_16x16x32_bf16(a, b1, acc1, 0, 0, 0);
        acc2 = __builtin_amdgcn_mfma_f32_16x16x32_bf16(a, b2, acc2, 0, 0, 0);
        acc3 = __builtin_amdgcn_mfma_f32_16x16x32_bf16(a, b3, acc3, 0, 0, 0);
    }

    int grow0 = rbase + quad * 4;
    float s[4];
    int ro_prev = row_off[grow0];
#pragma unroll
    for (int r = 0; r < 4; ++r) {
        int nx = row_off[grow0 + r + 1];
        s[r] = rsqrtf((float)max(nx - ro_prev, 1));
        ro_prev = nx;
    }

    float bv0 = bias[cbase +  0 + m16];
    float bv1 = bias[cbase + 16 + m16];
    float bv2 = bias[cbase + 32 + m16];
    float bv3 = bias[cbase + 48 + m16];

#pragma unroll
    for (int r = 0; r < 4; ++r) {
        size_t rowoff = (size_t)(grow0 + r) * DOUT;
        out[rowoff + cbase +  0 + m16] = acc0[r] * s[r] + bv0;
        out[rowoff + cbase + 16 + m16] = acc1[r] * s[r] + bv1;
        out[rowoff + cbase + 32 + m16] = acc2[r] * s[r] + bv2;
        out[rowoff + cbase + 48 + m16] = acc3[r] * s[r] + bv3;
    }
}

extern "C" void kernel_launch(void* const* d_in, const int* in_sizes, int n_in,
                              void* d_out, int out_size, void* d_ws, size_t ws_size,
                              hipStream_t stream) {
    const float* feat      = (const float*)d_in[0];
    const float* edge_feat = (const float*)d_in[1];
    const int*   src       = (const int*)d_in[2];
    const int*   dst       = (const int*)d_in[3];
    const float* W         = (const float*)d_in[4];
    const float* bias      = (const float*)d_in[5];
    float* out = (float*)d_out;

    // common big arrays (all 256B-aligned by construction)
    unsigned short* h_bf  = (unsigned short*)d_ws;            // NN*256 bf16
    unsigned short* wt_bf = h_bf + (size_t)NN * DIN;          // 256*256 bf16
    unsigned short* featn = wt_bf + 256 * 256;                // NN*192 bf16

    // big path layout: eperm directly after featn (256B-aligned)
    unsigned short* eperm = featn + (size_t)NN * 192;         // NE*64 bf16
    int*   perm_b     = (int*)(eperm + (size_t)NE * 64);      // NE int
    int*   row_off_b  = perm_b + NE;                          // NN+2
    float* odeg_inv_b = (float*)(row_off_b + NN + 2);         // NN
    int*   cursor_b   = (int*)(odeg_inv_b + NN);              // NN
    int*   bsum_b     = cursor_b + NN;                        // 256
    size_t need = (size_t)((char*)(bsum_b + 256) - (char*)d_ws);

    // fallback layout (round-1): meta after featn, perm2 after bsum
    int*   row_off_s  = (int*)(featn + (size_t)NN * 192);
    float* odeg_inv_s = (float*)(row_off_s + NN + 2);
    int*   cursor_s   = (int*)(odeg_inv_s + NN);
    int*   bsum_s     = cursor_s + NN;
    int2*  perm2      = (int2*)(bsum_s + 256);

    bool big_ws = (ws_size >= need);

    int*   row_off  = big_ws ? row_off_b  : row_off_s;
    float* odeg_inv = big_ws ? odeg_inv_b : odeg_inv_s;
    int*   cursor   = big_ws ? cursor_b   : cursor_s;
    int*   bsum     = big_ws ? bsum_b     : bsum_s;
    int*   in_cnt   = big_ws ? perm_b     : (int*)perm2;      // alias (early)
    int*   out_cnt  = in_cnt + NN;                            // alias (early)

    const int SCAN_BLOCKS = (NN + 255) / 256;   // 196

    zero_meta<<<(2 * NN + 255) / 256, 256, 0, stream>>>(in_cnt, 2 * NN);
    count_kernel<<<(NE + 255) / 256, 256, 0, stream>>>(src, dst, in_cnt, out_cnt);
    scan1<<<SCAN_BLOCKS, 256, 0, stream>>>(in_cnt, row_off, bsum);
    scan2<<<1, 256, 0, stream>>>(bsum, SCAN_BLOCKS);
    scan3<<<(NN + 256) / 256, 256, 0, stream>>>(row_off, cursor, odeg_inv, out_cnt, bsum);
    wconv<<<256, 256, 0, stream>>>(W, wt_bf);
    if (big_ws) {
        // fill BEFORE featconv so featn stays L3-resident for agg_gemm
        fill_kernel<<<NE / 16, 256, 0, stream>>>(src, dst, cursor, perm_b,
                                                 eperm, edge_feat);
        featconv<<<(NN + 3) / 4, 256, 0, stream>>>(feat, odeg_inv, featn);
        agg_gemm<<<NN / 16, 256, 0, stream>>>(featn, eperm, row_off, perm_b,
                                              wt_bf, bias, out);
    } else {
        featconv<<<(NN + 3) / 4, 256, 0, stream>>>(feat, odeg_inv, featn);
        fill_fb<<<(NE + 255) / 256, 256, 0, stream>>>(src, dst, cursor, perm2);
        aggregate_fb<<<(NN + 3) / 4, 256, 0, stream>>>(featn, edge_feat, row_off,
                                                       perm2, h_bf);
        gemm_mfma<<<NN / 16, 256, 0, stream>>>(h_bf, wt_bf, bias, row_off, out);
    }
}